// Round 18
// baseline (841.873 us; speedup 1.0000x reference)
//
#include <hip/hip_runtime.h>
#include <hip/hip_bf16.h>

#define B_ 2048
#define S_ 71
#define SP 72               // padded stride for at/ai
#define D_ 768
#define H_ 4
#define DH_ 192
#define TD2 1536            // q,k only
#define M_ (B_ * S_)        // 145408 = 1136*128
#define TEXT_ 35
#define NKT 12              // 768 / 64 K-tiles

typedef unsigned short u16;
typedef unsigned char u8;
typedef unsigned int u32;
typedef __attribute__((ext_vector_type(4))) float f32x4;
typedef __attribute__((ext_vector_type(8))) short bf16x8;

__device__ __forceinline__ u16 f2bf(float f) {
  u32 u = __float_as_uint(f);
  u32 r = (u + 0x7FFFu + ((u >> 16) & 1u)) >> 16;  // RNE
  return (u16)r;
}
__device__ __forceinline__ float bf2f(u16 x) {
  return __uint_as_float(((u32)x) << 16);
}
__device__ __forceinline__ u32 pk2bf(float lo, float hi) {
  __hip_bfloat162 h = __float22bfloat162_rn(float2{lo, hi});
  return *reinterpret_cast<u32*>(&h);
}

// ---- fp8 e4m3fn (OCP), POSITIVE values only (phi > 0) --------------------
__device__ __forceinline__ u8 f2fp8(float f) {
  if (f >= 448.0f) return 0x7E;                 // clamp to max finite
  u32 u = __float_as_uint(f);
  int e = (int)((u >> 23) & 0xFF) - 127;
  if (e >= -6) {                                 // normal range
    u32 m = u & 0x7FFFFF;
    u32 keep = m >> 20, rest = m & 0xFFFFF;
    u32 r = keep + ((rest > 0x80000u) || (rest == 0x80000u && (keep & 1)));
    return (u8)((((u32)(e + 7)) << 3) + r);      // carry rolls into exp
  }
  if (e < -10) return 0;
  return (u8)__float2int_rn(f * 512.0f);         // subnormal: m * 2^-9
}
__device__ __forceinline__ float fp82f(u32 v) {
  u32 e = (v >> 3) & 0xF, m = v & 7;
  if (e) return __uint_as_float(((e + 120) << 23) | (m << 20));
  return (float)m * 0.001953125f;                // 2^-9
}
__device__ __forceinline__ void dec4(u32 w, u32& lo, u32& hi) {
  lo = pk2bf(fp82f(w & 0xFF), fp82f((w >> 8) & 0xFF));
  hi = pk2bf(fp82f((w >> 16) & 0xFF), fp82f(w >> 24));
}

typedef __attribute__((address_space(1))) const unsigned int GASU;
typedef __attribute__((address_space(3))) unsigned int LASU;
__device__ __forceinline__ void gload16(const void* g, void* l) {
  __builtin_amdgcn_global_load_lds((GASU*)g, (LASU*)l, 16, 0, 0);
}

#define PHASE_BAR() do { __builtin_amdgcn_s_barrier(); asm volatile("" ::: "memory"); } while (0)
#define LGKM0() do { asm volatile("s_waitcnt lgkmcnt(0)" ::: "memory"); __builtin_amdgcn_sched_barrier(0); } while (0)

// ---------------------------------------------------------------------------
__global__ __launch_bounds__(256) void k_cvt_bf16(const float* __restrict__ in,
                                                  u16* __restrict__ out, int n8) {
  int idx = blockIdx.x * 256 + threadIdx.x;
  if (idx >= n8) return;
  const float4* p = (const float4*)(in + (size_t)idx * 8);
  float4 a = p[0], b = p[1];
  uint4 o;
  o.x = pk2bf(a.x, a.y);
  o.y = pk2bf(a.z, a.w);
  o.z = pk2bf(b.x, b.y);
  o.w = pk2bf(b.z, b.w);
  *(uint4*)(out + (size_t)idx * 8) = o;
}

// ---------------------------------------------------------------------------
// Main GEMM — q,k only: C[M,1536] = phi(A(fp32) * Wqk^T + bias), fp8-e4m3 out.
// 128x256, BK=64, A reg-staged dbuf, B gload_lds, 64KB LDS, 2 blocks/CU.
__global__ __launch_bounds__(512, 4) void k_gemm_qkv(
    const float* __restrict__ Afp,  // [M_,768] fp32 (features)
    const u16* __restrict__ Bw,     // [2304,768] bf16 (rows 0..1535 used)
    const float* __restrict__ bias, // [2304]
    u8* __restrict__ C)             // [M_,1536] fp8, phi everywhere
{
  __shared__ u16 sm[32768];   // 64 KiB
  int t = threadIdx.x;
  int lane = t & 63, wid = t >> 6;
  int wr = wid >> 2, wc = wid & 3;
  int lr = lane & 15;
  int g4 = lane >> 4;

  // XCD-bijective swizzle: nwg = 6816 = 8*852
  int swz = (blockIdx.x & 7) * 852 + (blockIdx.x >> 3);
  int bm = swz / 6, bn = swz % 6;
  const size_t arow0 = (size_t)bm * 128;
  const int bcol0 = bn * 256;

  const float* srcAf[2];
  int dA[2];
#pragma unroll
  for (int j = 0; j < 2; ++j) {
    int c = j * 512 + t;
    srcAf[j] = Afp + (arow0 + (c >> 3)) * 768 + ((c & 7) ^ ((c >> 3) & 7)) * 8;
    dA[j] = c * 8;
  }
  const u16* srcB[4];
  int dB[4];
#pragma unroll
  for (int j = 0; j < 4; ++j) {
    int c = j * 512 + t;
    srcB[j] = Bw + (size_t)(bcol0 + (c >> 3)) * 768 + ((c & 7) ^ ((c >> 3) & 7)) * 8;
    dB[j] = 16384 + c * 8;
  }

#define STAGE_B(ktu) do { \
  gload16(srcB[0] + (ktu), &sm[dB[0]]); \
  gload16(srcB[1] + (ktu), &sm[dB[1]]); \
  gload16(srcB[2] + (ktu), &sm[dB[2]]); \
  gload16(srcB[3] + (ktu), &sm[dB[3]]); \
} while (0)
#define LOADA(ktu) do { \
  fa0 = *(const float4*)(srcAf[0] + (ktu)); \
  fa1 = *(const float4*)(srcAf[0] + (ktu) + 4); \
  fa2 = *(const float4*)(srcAf[1] + (ktu)); \
  fa3 = *(const float4*)(srcAf[1] + (ktu) + 4); \
} while (0)
#define WRITEA(abuf) do { \
  uint4 o0; \
  o0.x = pk2bf(fa0.x, fa0.y); o0.y = pk2bf(fa0.z, fa0.w); \
  o0.z = pk2bf(fa1.x, fa1.y); o0.w = pk2bf(fa1.z, fa1.w); \
  *(uint4*)(&sm[(abuf) + dA[0]]) = o0; \
  uint4 o1; \
  o1.x = pk2bf(fa2.x, fa2.y); o1.y = pk2bf(fa2.z, fa2.w); \
  o1.z = pk2bf(fa3.x, fa3.y); o1.w = pk2bf(fa3.z, fa3.w); \
  *(uint4*)(&sm[(abuf) + dA[1]]) = o1; \
} while (0)

  int gx0 = g4 ^ (lr & 7);
  int aro = (wr * 64 + lr) * 64;
  int bro = 16384 + (wc * 64 + lr) * 64;

  f32x4 acc[4][4] = {};
  float4 fa0, fa1, fa2, fa3;

  LOADA(0);
  STAGE_B(0);
  asm volatile("s_waitcnt vmcnt(0)" ::: "memory");
  WRITEA(0);
  asm volatile("s_waitcnt lgkmcnt(0)" ::: "memory");
  PHASE_BAR();

  int curA = 0;
  for (int T = 0; T < NKT; ++T) {
    int nxtA = 8192 - curA;
    bool pf = (T < NKT - 1);
    int ktu = (T + 1) * 64;
    bf16x8 b0[4], a0[4];
#pragma unroll
    for (int ni = 0; ni < 4; ++ni) b0[ni] = *(const bf16x8*)(&sm[bro + ni * 1024 + gx0 * 8]);
#pragma unroll
    for (int mi = 0; mi < 4; ++mi) a0[mi] = *(const bf16x8*)(&sm[curA + aro + mi * 1024 + gx0 * 8]);
    __builtin_amdgcn_s_setprio(1);
#pragma unroll
    for (int mi = 0; mi < 4; ++mi)
#pragma unroll
      for (int ni = 0; ni < 4; ++ni)
        acc[mi][ni] = __builtin_amdgcn_mfma_f32_16x16x32_bf16(a0[mi], b0[ni], acc[mi][ni], 0, 0, 0);
    __builtin_amdgcn_s_setprio(0);
    int gx1 = gx0 ^ 4;
    bf16x8 b1[4];
#pragma unroll
    for (int ni = 0; ni < 4; ++ni) b1[ni] = *(const bf16x8*)(&sm[bro + ni * 1024 + gx1 * 8]);
    LGKM0();
    PHASE_BAR();
    if (pf) { STAGE_B(ktu); LOADA(ktu); }
    bf16x8 a1[4];
#pragma unroll
    for (int mi = 0; mi < 4; ++mi) a1[mi] = *(const bf16x8*)(&sm[curA + aro + mi * 1024 + gx1 * 8]);
    __builtin_amdgcn_s_setprio(1);
#pragma unroll
    for (int mi = 0; mi < 4; ++mi)
#pragma unroll
      for (int ni = 0; ni < 4; ++ni)
        acc[mi][ni] = __builtin_amdgcn_mfma_f32_16x16x32_bf16(a1[mi], b1[ni], acc[mi][ni], 0, 0, 0);
    __builtin_amdgcn_s_setprio(0);
    if (pf) {
      asm volatile("s_waitcnt vmcnt(0)" ::: "memory");
      WRITEA(nxtA);
      asm volatile("s_waitcnt lgkmcnt(0)" ::: "memory");
      PHASE_BAR();
    }
    curA = nxtA;
  }

#pragma unroll
  for (int mi = 0; mi < 4; ++mi) {
#pragma unroll
    for (int ni = 0; ni < 4; ++ni) {
      int col = bcol0 + wc * 64 + ni * 16 + lr;
      float bb = bias[col];
#pragma unroll
      for (int i = 0; i < 4; ++i) {
        size_t row = arow0 + wr * 64 + mi * 16 + g4 * 4 + i;
        float v = acc[mi][ni][i] + bb;
        v = (v > 0.0f) ? (v + 1.0f) : __expf(v);   // phi (q,k) — positive
        C[row * TD2 + col] = f2fp8(v);
      }
    }
  }
#undef STAGE_B
#undef LOADA
#undef WRITEA
}

// ---------------------------------------------------------------------------
// Attention qk-phases: one block per (b,h). QK is fp8; staging decodes
// fp8 -> bf16 into LDS (phases unchanged from round 17).
#define ALD 200

__global__ __launch_bounds__(256) void k_attn_qk(
    const u8* __restrict__ qk,    // [M_,1536] fp8 (phi applied)
    float* __restrict__ AT,       // [B_,4,SP]
    float* __restrict__ AI,       // [B_,4,SP]
    float* __restrict__ sat)      // [4096,4]
{
  __shared__ u16 qs[S_ * ALD];
  __shared__ u16 ks[S_ * ALD];
  __shared__ float z[DH_], qt[DH_], qi[DH_], wt[S_], wi[S_];
  __shared__ float zp[4][DH_];
  __shared__ float qp[4][DH_], qip[4][DH_];
  __shared__ float at_l[S_ + 1], ai_l[S_ + 1];
  int t = threadIdx.x;
  int b = blockIdx.x >> 2, h = blockIdx.x & 3;
  size_t base = (size_t)b * S_ * TD2;
  int qoff = h * DH_, koff = 768 + h * DH_;
  int grp = t >> 4, gl = t & 15;
  int w = t >> 6, ln = t & 63;

  // stage q,k: 16-byte fp8 chunks -> 16 bf16 (32B) per chunk
  for (int idx = t; idx < S_ * 12; idx += 256) {
    int s = idx / 12, c = (idx % 12) * 16;
    size_t gb = base + (size_t)s * TD2;
    uint4 rq = *(const uint4*)(&qk[gb + qoff + c]);
    uint4 rk = *(const uint4*)(&qk[gb + koff + c]);
    uint4 q0, q1, k0, k1;
    dec4(rq.x, q0.x, q0.y); dec4(rq.y, q0.z, q0.w);
    dec4(rq.z, q1.x, q1.y); dec4(rq.w, q1.z, q1.w);
    dec4(rk.x, k0.x, k0.y); dec4(rk.y, k0.z, k0.w);
    dec4(rk.z, k1.x, k1.y); dec4(rk.w, k1.z, k1.w);
    *(uint4*)(&qs[s * ALD + c]) = q0;
    *(uint4*)(&qs[s * ALD + c + 8]) = q1;
    *(uint4*)(&ks[s * ALD + c]) = k0;
    *(uint4*)(&ks[s * ALD + c + 8]) = k1;
  }
  __syncthreads();
  // z[d] = sum_s k[s,d] — wave-parallel partials
  {
    int s0 = w * 18, s1 = (w == 3) ? S_ : (s0 + 18);
    float p0 = 0, p1 = 0, p2 = 0;
    for (int s = s0; s < s1; ++s) {
      p0 += bf2f(ks[s * ALD + ln]);
      p1 += bf2f(ks[s * ALD + ln + 64]);
      p2 += bf2f(ks[s * ALD + ln + 128]);
    }
    zp[w][ln] = p0; zp[w][ln + 64] = p1; zp[w][ln + 128] = p2;
  }
  __syncthreads();
  if (t < DH_) z[t] = (zp[0][t] + zp[1][t]) + (zp[2][t] + zp[3][t]);
  __syncthreads();
  // den[s] = q[s,:].z — 16-lane-group parallel
  for (int s = grp; s < S_; s += 16) {
    float a = 0;
    int d0 = gl * 12;
#pragma unroll
    for (int i = 0; i < 12; ++i) a += bf2f(qs[s * ALD + d0 + i]) * z[d0 + i];
#pragma unroll
    for (int o = 8; o >= 1; o >>= 1) a += __shfl_xor(a, o);
    if (gl == 0) {
      float den = a + 1e-6f;
      wt[s] = (s < TEXT_) ? 1.0f / (35.0f * den) : 0.0f;
      wi[s] = (s >= TEXT_) ? 1.0f / (36.0f * den) : 0.0f;
    }
  }
  __syncthreads();
  // qt[d], qi[d] — wave-parallel partials
  {
    int s0 = w * 18, s1 = (w == 3) ? S_ : (s0 + 18);
    float pt0 = 0, pt1 = 0, pt2 = 0, pi0 = 0, pi1 = 0, pi2 = 0;
    for (int s = s0; s < s1; ++s) {
      float wts = wt[s], wis = wi[s];
      float q0 = bf2f(qs[s * ALD + ln]);
      float q1 = bf2f(qs[s * ALD + ln + 64]);
      float q2 = bf2f(qs[s * ALD + ln + 128]);
      pt0 += q0 * wts; pt1 += q1 * wts; pt2 += q2 * wts;
      pi0 += q0 * wis; pi1 += q1 * wis; pi2 += q2 * wis;
    }
    qp[w][ln] = pt0; qp[w][ln + 64] = pt1; qp[w][ln + 128] = pt2;
    qip[w][ln] = pi0; qip[w][ln + 64] = pi1; qip[w][ln + 128] = pi2;
  }
  __syncthreads();
  if (t < DH_) {
    qt[t] = (qp[0][t] + qp[1][t]) + (qp[2][t] + qp[3][t]);
    qi[t] = (qip[0][t] + qip[1][t]) + (qip[2][t] + qip[3][t]);
  }
  __syncthreads();
  // at[s], ai[s] — group parallel
  size_t arow = ((size_t)b * 4 + h) * SP;
  for (int s = grp; s < S_; s += 16) {
    float aT = 0, aI = 0;
    int d0 = gl * 12;
#pragma unroll
    for (int i = 0; i < 12; ++i) {
      float kv = bf2f(ks[s * ALD + d0 + i]);
      aT += kv * qt[d0 + i]; aI += kv * qi[d0 + i];
    }
#pragma unroll
    for (int o = 8; o >= 1; o >>= 1) { aT += __shfl_xor(aT, o); aI += __shfl_xor(aI, o); }
    if (gl == 0) {
      at_l[s] = aT; ai_l[s] = aI;
      AT[arow + s] = aT; AI[arow + s] = aI;
    }
  }
  __syncthreads();
  if (t < 64) {
    float vT = at_l[t] + ((t < 7) ? at_l[t + 64] : 0.0f);
    float vI = ai_l[t] + ((t < 7) ? ai_l[t + 64] : 0.0f);
#pragma unroll
    for (int o = 32; o >= 1; o >>= 1) { vT += __shfl_xor(vT, o); vI += __shfl_xor(vI, o); }
    if (t == 0) {
      sat[(size_t)b * 4 + h] = vT;
      sat[(size_t)(2048 + b) * 4 + h] = vI;
    }
  }
}

// ---------------------------------------------------------------------------
// Y accumulation: block per b, 192 threads; streams x once (float4).
__global__ __launch_bounds__(192) void k_accy(
    const float* __restrict__ x,  // [B_,71,768] fp32
    const float* __restrict__ AT, // [B_,4,SP]
    const float* __restrict__ AI,
    u16* __restrict__ Y)          // [4096,3072] bf16
{
  __shared__ float at_s[4][S_], ai_s[4][S_];
  int t = threadIdx.x, b = blockIdx.x;
  for (int i = t; i < 4 * S_; i += 192) {
    int h = i / S_, s = i % S_;
    at_s[h][s] = AT[((size_t)b * 4 + h) * SP + s];
    ai_s[h][s] = AI[((size_t)b * 4 + h) * SP + s];
  }
  __syncthreads();
  float4 yt[4] = {}, yi[4] = {};
  const float4* xb = (const float4*)(x + (size_t)b * S_ * 768);
  for (int s = 0; s < S_; ++s) {
    float4 xv = xb[s * 192 + t];
#pragma unroll
    for (int h = 0; h < 4; ++h) {
      float a = at_s[h][s], ai_ = ai_s[h][s];
      yt[h].x += a * xv.x; yt[h].y += a * xv.y; yt[h].z += a * xv.z; yt[h].w += a * xv.w;
      yi[h].x += ai_ * xv.x; yi[h].y += ai_ * xv.y; yi[h].z += ai_ * xv.z; yi[h].w += ai_ * xv.w;
    }
  }
  size_t rt = (size_t)b * 3072, ri = (size_t)(2048 + b) * 3072;
#pragma unroll
  for (int h = 0; h < 4; ++h) {
    uint2 ot, oi;
    ot.x = pk2bf(yt[h].x, yt[h].y); ot.y = pk2bf(yt[h].z, yt[h].w);
    oi.x = pk2bf(yi[h].x, yi[h].y); oi.y = pk2bf(yi[h].z, yi[h].w);
    *(uint2*)(&Y[rt + h * 768 + t * 4]) = ot;
    *(uint2*)(&Y[ri + h * 768 + t * 4]) = oi;
  }
}

// ---------------------------------------------------------------------------
// Grouped v-GEMM: G[4096][768] = Y_h * Wv_h^T + sat*bv (per head h).
__global__ __launch_bounds__(256, 4) void k_gemm_v(
    const u16* __restrict__ Yb,    // [4096,3072] bf16
    const u16* __restrict__ Wbf,   // [2304,768] bf16 (rows 1536+ = Wv)
    const float* __restrict__ bqkv,
    const float* __restrict__ sat, // [4096,4]
    u16* __restrict__ G)           // [4096,768] bf16
{
  __shared__ u16 sm[24576];
  int t = threadIdx.x;
  int lane = t & 63, wid = t >> 6;
  int wr = wid >> 1, wc = wid & 1;
  int lr = lane & 15, g4 = lane >> 4;
  int bm = blockIdx.x / 12, nt = blockIdx.x % 12;
  int h = nt / 3, e0 = (nt % 3) * 64;
  const size_t arow0 = (size_t)bm * 128;

  const u16* srcA[4];
  int dA[4];
#pragma unroll
  for (int j = 0; j < 4; ++j) {
    int c = j * 256 + t;
    int row = c >> 3, kg = (c & 7) ^ (row & 7);
    srcA[j] = Yb + (arow0 + row) * 3072 + h * 768 + kg * 8;
    dA[j] = c * 8;
  }
  const u16* srcB[2];
  int dB[2];
#pragma unroll
  for (int j = 0; j < 2; ++j) {
    int c = j * 256 + t;
    int row = c >> 3, kg = (c & 7) ^ (row & 7);
    srcB[j] = Wbf + (size_t)(1536 + h * DH_ + e0 + row) * 768 + kg * 8;
    dB[j] = c * 8;
  }

#define VSTAGE(abuf, bbuf, ktu) do { \
  gload16(srcA[0] + (ktu), &sm[(abuf) + dA[0]]); \
  gload16(srcA[1] + (ktu), &sm[(abuf) + dA[1]]); \
  gload16(srcA[2] + (ktu), &sm[(abuf) + dA[2]]); \
  gload16(srcA[3] + (ktu), &sm[(abuf) + dA[3]]); \
  gload16(srcB[0] + (ktu), &sm[(bbuf) + dB[0]]); \
  gload16(srcB[1] + (ktu), &sm[(bbuf) + dB[1]]); \
} while (0)

  int gx0 = g4 ^ (lr & 7);
  int aro = (wr * 64 + lr) * 64;
  int bro = (wc * 32 + lr) * 64;

  f32x4 acc[4][2] = {};

  VSTAGE(0, 16384, 0);
  asm volatile("s_waitcnt vmcnt(0)" ::: "memory");
  PHASE_BAR();

  for (int T = 0; T < NKT; ++T) {
    int abuf = (T & 1) * 8192, bbuf = 16384 + (T & 1) * 4096;
    bool pf = (T < NKT - 1);
    if (pf) VSTAGE(8192 - abuf, 20480 - (T & 1) * 4096, (T + 1) * 64);
#pragma unroll
    for (int kk = 0; kk < 2; ++kk) {
      int gx = gx0 ^ (kk * 4);
      bf16x8 a[4], bfr[2];
#pragma unroll
      for (int mi = 0; mi < 4; ++mi) a[mi] = *(const bf16x8*)(&sm[abuf + aro + mi * 1024 + gx * 8]);
#pragma unroll
      for (int ni = 0; ni < 2; ++ni) bfr[ni] = *(const bf16x8*)(&sm[bbuf + bro + ni * 1024 + gx * 8]);
#pragma unroll
      for (int mi = 0; mi < 4; ++mi)
#pragma unroll
        for (int ni = 0; ni < 2; ++ni)
          acc[mi][ni] = __builtin_amdgcn_mfma_f32_16x16x32_bf16(a[mi], bfr[ni], acc[mi][ni], 0, 0, 0);
    }
    if (pf) {
      asm volatile("s_waitcnt vmcnt(0)" ::: "memory");
      PHASE_BAR();
    }
  }

#pragma unroll
  for (int mi = 0; mi < 4; ++mi) {
#pragma unroll
    for (int ni = 0; ni < 2; ++ni) {
      int e = e0 + wc * 32 + ni * 16 + lr;
      int gcol = h * DH_ + e;
      float bv = bqkv[1536 + gcol];
#pragma unroll
      for (int i = 0; i < 4; ++i) {
        size_t row = arow0 + wr * 64 + mi * 16 + g4 * 4 + i;
        G[row * 768 + gcol] = f2bf(acc[mi][ni][i] + sat[row * 4 + h] * bv);
      }
    }
  }
#undef VSTAGE
}

// ---------------------------------------------------------------------------
// Head GEMM: F = tanh(G * w_out^T + b_out)
__global__ __launch_bounds__(512, 4) void k_gemm_head(
    const u16* __restrict__ Gb,   // [4096,768] bf16
    const u16* __restrict__ Wo,   // [768,768] bf16 (n-major)
    const float* __restrict__ bout,
    u16* __restrict__ F)          // [4096,768] bf16
{
  __shared__ u16 sm[32768];
  int t = threadIdx.x;
  int lane = t & 63, wid = t >> 6;
  int wr = wid >> 2, wc = wid & 3;
  int lr = lane & 15;
  int g4 = lane >> 4;

  int bm = blockIdx.x / 3, bn = blockIdx.x % 3;
  const size_t arow0 = (size_t)bm * 128;
  const int bcol0 = bn * 256;

  const u16* srcA[2];
  int dA[2];
#pragma unroll
  for (int j = 0; j < 2; ++j) {
    int c = j * 512 + t;
    srcA[j] = Gb + (arow0 + (c >> 3)) * 768 + ((c & 7) ^ ((c >> 3) & 7)) * 8;
    dA[j] = c * 8;
  }
  const u16* srcB[4];
  int dB[4];
#pragma unroll
  for (int j = 0; j < 4; ++j) {
    int c = j * 512 + t;
    srcB[j] = Wo + (size_t)(bcol0 + (c >> 3)) * 768 + ((c & 7) ^ ((c >> 3) & 7)) * 8;
    dB[j] = 16384 + c * 8;
  }

#define STAGE_A2(abuf, ktu) do { \
  gload16(srcA[0] + (ktu), &sm[(abuf) + dA[0]]); \
  gload16(srcA[1] + (ktu), &sm[(abuf) + dA[1]]); \
} while (0)
#define STAGE_B2(ktu) do { \
  gload16(srcB[0] + (ktu), &sm[dB[0]]); \
  gload16(srcB[1] + (ktu), &sm[dB[1]]); \
  gload16(srcB[2] + (ktu), &sm[dB[2]]); \
  gload16(srcB[3] + (ktu), &sm[dB[3]]); \
} while (0)

  int gx0 = g4 ^ (lr & 7);
  int aro = (wr * 64 + lr) * 64;
  int bro = 16384 + (wc * 64 + lr) * 64;

  f32x4 acc[4][4] = {};

  STAGE_A2(0, 0); STAGE_B2(0);
  asm volatile("s_waitcnt vmcnt(0)" ::: "memory");
  PHASE_BAR();

  int curA = 0;
  for (int T = 0; T < NKT; ++T) {
    int nxtA = 8192 - curA;
    bool pf = (T < NKT - 1);
    int ktu = (T + 1) * 64;
    bf16x8 bfr[4][2];
#pragma unroll
    for (int ni = 0; ni < 4; ++ni) {
      bfr[ni][0] = *(const bf16x8*)(&sm[bro + ni * 1024 + gx0 * 8]);
      bfr[ni][1] = *(const bf16x8*)(&sm[bro + ni * 1024 + (gx0 ^ 4) * 8]);
    }
    LGKM0();
    PHASE_BAR();
    if (pf) { STAGE_B2(ktu); STAGE_A2(nxtA, ktu); }
    __builtin_amdgcn_s_setprio(1);
#pragma unroll
    for (int kk = 0; kk < 2; ++kk) {
      int gx = gx0 ^ (kk * 4);
      bf16x8 afr[4];
#pragma unroll
      for (int mi = 0; mi < 4; ++mi)
        afr[mi] = *(const bf16x8*)(&sm[curA + aro + mi * 1024 + gx * 8]);
#pragma unroll
      for (int mi = 0; mi < 4; ++mi)
#pragma unroll
        for (int ni = 0; ni < 4; ++ni)
          acc[mi][ni] = __builtin_amdgcn_mfma_f32_16x16x32_bf16(afr[mi], bfr[ni][kk], acc[mi][ni], 0, 0, 0);
    }
    __builtin_amdgcn_s_setprio(0);
    if (pf) {
      asm volatile("s_waitcnt vmcnt(0)" ::: "memory");
      PHASE_BAR();
    }
    curA = nxtA;
  }

#pragma unroll
  for (int mi = 0; mi < 4; ++mi) {
#pragma unroll
    for (int ni = 0; ni < 4; ++ni) {
      int col = bcol0 + wc * 64 + ni * 16 + lr;
      float bb = bout[col];
#pragma unroll
      for (int i = 0; i < 4; ++i) {
        size_t row = arow0 + wr * 64 + mi * 16 + g4 * 4 + i;
        F[row * 768 + col] = f2bf(tanhf(acc[mi][ni][i] + bb));
      }
    }
  }
#undef STAGE_A2
#undef STAGE_B2
}

// ---------------------------------------------------------------------------
#define GC 4
__global__ __launch_bounds__(256) void k_cos(
    const u16* __restrict__ F,    // [4096,768] bf16 (tanh applied)
    float* __restrict__ out)      // [B_]
{
  __shared__ float red[3][4];
  int t = threadIdx.x, b0 = blockIdx.x * GC;
  int lane = t & 63, wid = t >> 6;
  for (int g = 0; g < GC; ++g) {
    int b = b0 + g;
    float st = 0, si = 0, sd = 0;
#pragma unroll
    for (int j = 0; j < 3; ++j) {
      int c = t + j * 256;
      float rt = bf2f(F[(size_t)b * 768 + c]);
      float ri = bf2f(F[(size_t)(2048 + b) * 768 + c]);
      st += rt * rt; si += ri * ri; sd += rt * ri;
    }
#pragma unroll
    for (int off = 32; off >= 1; off >>= 1) {
      st += __shfl_down(st, off);
      si += __shfl_down(si, off);
      sd += __shfl_down(sd, off);
    }
    __syncthreads();
    if (lane == 0) { red[0][wid] = st; red[1][wid] = si; red[2][wid] = sd; }
    __syncthreads();
    if (t == 0) {
      float S1 = red[0][0] + red[0][1] + red[0][2] + red[0][3];
      float S2 = red[1][0] + red[1][1] + red[1][2] + red[1][3];
      float S3 = red[2][0] + red[2][1] + red[2][2] + red[2][3];
      out[b] = S3 / (fmaxf(sqrtf(S1), 1e-8f) * fmaxf(sqrtf(S2), 1e-8f));
    }
  }
}

// ---------------------------------------------------------------------------
extern "C" void kernel_launch(void* const* d_in, const int* in_sizes, int n_in,
                              void* d_out, int out_size, void* d_ws, size_t ws_size,
                              hipStream_t stream) {
  const float* features = (const float*)d_in[0];
  // d_in[1] = attention_mask (unused by forward)
  const float* w_qkv = (const float*)d_in[2];
  const float* b_qkv = (const float*)d_in[3];
  const float* w_out = (const float*)d_in[4];
  const float* b_out = (const float*)d_in[5];
  float* out = (float*)d_out;

  char* ws = (char*)d_ws;
  size_t off = 0;
  auto alloc = [&](size_t bytes) {
    void* p = ws + off;
    off += (bytes + 255) & ~(size_t)255;
    return p;
  };
  u8*  QK   = (u8*)alloc((size_t)M_ * TD2);          // 218 MB (fp8)
  u16* Wbf  = (u16*)alloc((size_t)2304 * D_ * 2);    // 3.5 MB
  u16* Wobf = (u16*)alloc((size_t)D_ * D_ * 2);      // 1.2 MB
  u16* Yv   = (u16*)alloc((size_t)4096 * 3072 * 2);  // 25 MB
  float* AT = (float*)alloc((size_t)B_ * 4 * SP * 4); // 2.4 MB
  float* AI = (float*)alloc((size_t)B_ * 4 * SP * 4); // 2.4 MB
  float* sat = (float*)alloc((size_t)4096 * 4 * 4);  // 64 KB
  u16* G    = (u16*)alloc((size_t)4096 * D_ * 2);    // 6.3 MB
  u16* F    = (u16*)alloc((size_t)4096 * D_ * 2);    // 6.3 MB
  (void)ws_size;

  hipLaunchKernelGGL(k_cvt_bf16, dim3((2304 * D_ / 8 + 255) / 256), dim3(256), 0, stream,
                     w_qkv, Wbf, 2304 * D_ / 8);
  hipLaunchKernelGGL(k_cvt_bf16, dim3((D_ * D_ / 8 + 255) / 256), dim3(256), 0, stream,
                     w_out, Wobf, D_ * D_ / 8);

  hipLaunchKernelGGL(k_gemm_qkv, dim3(6 * 1136), dim3(512), 0, stream,
                     features, Wbf, b_qkv, QK);
  hipLaunchKernelGGL(k_attn_qk, dim3(B_ * H_), dim3(256), 0, stream, QK, AT, AI, sat);
  hipLaunchKernelGGL(k_accy, dim3(B_), dim3(192), 0, stream, features, AT, AI, Yv);
  hipLaunchKernelGGL(k_gemm_v, dim3(32 * 12), dim3(256), 0, stream,
                     Yv, Wbf, b_qkv, sat, G);
  hipLaunchKernelGGL(k_gemm_head, dim3(32 * 3), dim3(512), 0, stream,
                     G, Wobf, b_out, F);
  hipLaunchKernelGGL(k_cos, dim3(B_ / GC), dim3(256), 0, stream, F, out);
}

// Round 19
// 785.989 us; speedup vs baseline: 1.0711x; 1.0711x over previous
//
#include <hip/hip_runtime.h>
#include <hip/hip_bf16.h>

#define B_ 2048
#define S_ 71
#define SP 72               // padded stride for at/ai
#define D_ 768
#define H_ 4
#define DH_ 192
#define TD2 1536            // q,k only
#define M_ (B_ * S_)        // 145408 = 2272*64
#define TEXT_ 35
#define NKT 12              // 768 / 64 K-tiles

typedef unsigned short u16;
typedef unsigned char u8;
typedef unsigned int u32;
typedef __attribute__((ext_vector_type(2))) float f32x2;
typedef __attribute__((ext_vector_type(4))) float f32x4;
typedef __attribute__((ext_vector_type(8))) short bf16x8;

__device__ __forceinline__ u16 f2bf(float f) {
  u32 u = __float_as_uint(f);
  u32 r = (u + 0x7FFFu + ((u >> 16) & 1u)) >> 16;  // RNE
  return (u16)r;
}
__device__ __forceinline__ float bf2f(u16 x) {
  return __uint_as_float(((u32)x) << 16);
}
__device__ __forceinline__ u32 pk2bf(float lo, float hi) {
  __hip_bfloat162 h = __float22bfloat162_rn(float2{lo, hi});
  return *reinterpret_cast<u32*>(&h);
}

// ---- fp8 e4m3 codec: HW single-instruction path (gfx940+), guarded -------
#if __has_builtin(__builtin_amdgcn_cvt_pk_fp8_f32) && __has_builtin(__builtin_amdgcn_cvt_pk_f32_fp8)
__device__ __forceinline__ u32 enc4fp8(float a, float b, float c, float d) {
  int w = 0;
  w = __builtin_amdgcn_cvt_pk_fp8_f32(a, b, w, false);
  w = __builtin_amdgcn_cvt_pk_fp8_f32(c, d, w, true);
  return (u32)w;
}
__device__ __forceinline__ void dec4(u32 w, u32& lo, u32& hi) {
  f32x2 a = __builtin_amdgcn_cvt_pk_f32_fp8((int)w, false);
  f32x2 b = __builtin_amdgcn_cvt_pk_f32_fp8((int)w, true);
  lo = pk2bf(a.x, a.y);
  hi = pk2bf(b.x, b.y);
}
#else
// branchless fallback (positive inputs)
__device__ __forceinline__ u8 f2fp8_1(float f) {
  f = fminf(f, 448.0f);
  u32 u = __float_as_uint(f);
  int e = (int)((u >> 23) & 0xFF) - 127;
  u32 m = u & 0x7FFFFF;
  u32 keep = m >> 20, rest = m & 0xFFFFF;
  u32 rb = (rest > 0x80000u) || (rest == 0x80000u && (keep & 1));
  u32 nrm = (((u32)(e + 7)) << 3) + keep + rb;
  u32 sub = (u32)__float2int_rn(f * 512.0f);
  u32 r = (e >= -6) ? nrm : ((e < -10) ? 0u : sub);
  return (u8)r;
}
__device__ __forceinline__ u32 enc4fp8(float a, float b, float c, float d) {
  return (u32)f2fp8_1(a) | ((u32)f2fp8_1(b) << 8) | ((u32)f2fp8_1(c) << 16) | ((u32)f2fp8_1(d) << 24);
}
__device__ __forceinline__ float fp82f(u32 v) {
  u32 e = (v >> 3) & 0xF, m = v & 7;
  float nrm = __uint_as_float(((e + 120) << 23) | (m << 20));
  return e ? nrm : (float)m * 0.001953125f;
}
__device__ __forceinline__ void dec4(u32 w, u32& lo, u32& hi) {
  lo = pk2bf(fp82f(w & 0xFF), fp82f((w >> 8) & 0xFF));
  hi = pk2bf(fp82f((w >> 16) & 0xFF), fp82f(w >> 24));
}
#endif

typedef __attribute__((address_space(1))) const unsigned int GASU;
typedef __attribute__((address_space(3))) unsigned int LASU;
__device__ __forceinline__ void gload16(const void* g, void* l) {
  __builtin_amdgcn_global_load_lds((GASU*)g, (LASU*)l, 16, 0, 0);
}

#define PHASE_BAR() do { __builtin_amdgcn_s_barrier(); asm volatile("" ::: "memory"); } while (0)
#define LGKM0() do { asm volatile("s_waitcnt lgkmcnt(0)" ::: "memory"); __builtin_amdgcn_sched_barrier(0); } while (0)

// ---------------------------------------------------------------------------
__global__ __launch_bounds__(256) void k_cvt_bf16(const float* __restrict__ in,
                                                  u16* __restrict__ out, int n8) {
  int idx = blockIdx.x * 256 + threadIdx.x;
  if (idx >= n8) return;
  const float4* p = (const float4*)(in + (size_t)idx * 8);
  float4 a = p[0], b = p[1];
  uint4 o;
  o.x = pk2bf(a.x, a.y);
  o.y = pk2bf(a.z, a.w);
  o.z = pk2bf(b.x, b.y);
  o.w = pk2bf(b.z, b.w);
  *(uint4*)(out + (size_t)idx * 8) = o;
}

// ---------------------------------------------------------------------------
// Main GEMM — q,k only, fp8 out via HW codec. OCCUPANCY retile: 64x256 tile,
// BK=64, 4 waves (each 64x64), A fp32 reg-staged dbuf (2x8KB) + B gload_lds
// single (32KB) = 48KB LDS -> 3 blocks/CU (launch_bounds(256,3)). Per-wave
// economics identical to the 128x256 build (2 A-granules/thread, 32 MFMA/
// tile/wave); 3 independent barrier domains hide the vmcnt drains.
__global__ __launch_bounds__(256, 3) void k_gemm_qkv(
    const float* __restrict__ Afp,  // [M_,768] fp32 (features)
    const u16* __restrict__ Bw,     // [2304,768] bf16 (rows 0..1535 used)
    const float* __restrict__ bias, // [2304]
    u8* __restrict__ C)             // [M_,1536] fp8, phi everywhere
{
  // u16 units: A0 [0,4096), A1 [4096,8192), B [8192,24576)
  __shared__ u16 sm[24576];   // 48 KiB
  int t = threadIdx.x;
  int lane = t & 63, wc = t >> 6;      // 4 waves: wave wc covers cols wc*64
  int lr = lane & 15;
  int g4 = lane >> 4;

  // XCD-bijective swizzle: nwg = 13632 = 8*1704; bn inner -> A-panel L2 reuse
  int swz = (blockIdx.x & 7) * 1704 + (blockIdx.x >> 3);
  int bm = swz / 6, bn = swz % 6;
  const size_t arow0 = (size_t)bm * 64;
  const int bcol0 = bn * 256;

  // A: 512 granules (8 elems), 2/thread; source granule pre-swizzled.
  const float* srcAf[2];
  int dA[2];
#pragma unroll
  for (int j = 0; j < 2; ++j) {
    int c = j * 256 + t;
    srcAf[j] = Afp + (arow0 + (c >> 3)) * 768 + ((c & 7) ^ ((c >> 3) & 7)) * 8;
    dA[j] = c * 8;
  }
  // B: 2048 granules, 8/thread via gload_lds.
  const u16* srcB[8];
  int dB[8];
#pragma unroll
  for (int j = 0; j < 8; ++j) {
    int c = j * 256 + t;
    srcB[j] = Bw + (size_t)(bcol0 + (c >> 3)) * 768 + ((c & 7) ^ ((c >> 3) & 7)) * 8;
    dB[j] = 8192 + c * 8;
  }

#define STAGE_B(ktu) do { \
  gload16(srcB[0] + (ktu), &sm[dB[0]]); \
  gload16(srcB[1] + (ktu), &sm[dB[1]]); \
  gload16(srcB[2] + (ktu), &sm[dB[2]]); \
  gload16(srcB[3] + (ktu), &sm[dB[3]]); \
  gload16(srcB[4] + (ktu), &sm[dB[4]]); \
  gload16(srcB[5] + (ktu), &sm[dB[5]]); \
  gload16(srcB[6] + (ktu), &sm[dB[6]]); \
  gload16(srcB[7] + (ktu), &sm[dB[7]]); \
} while (0)
#define LOADA(ktu) do { \
  fa0 = *(const float4*)(srcAf[0] + (ktu)); \
  fa1 = *(const float4*)(srcAf[0] + (ktu) + 4); \
  fa2 = *(const float4*)(srcAf[1] + (ktu)); \
  fa3 = *(const float4*)(srcAf[1] + (ktu) + 4); \
} while (0)
#define WRITEA(abuf) do { \
  uint4 o0; \
  o0.x = pk2bf(fa0.x, fa0.y); o0.y = pk2bf(fa0.z, fa0.w); \
  o0.z = pk2bf(fa1.x, fa1.y); o0.w = pk2bf(fa1.z, fa1.w); \
  *(uint4*)(&sm[(abuf) + dA[0]]) = o0; \
  uint4 o1; \
  o1.x = pk2bf(fa2.x, fa2.y); o1.y = pk2bf(fa2.z, fa2.w); \
  o1.z = pk2bf(fa3.x, fa3.y); o1.w = pk2bf(fa3.z, fa3.w); \
  *(uint4*)(&sm[(abuf) + dA[1]]) = o1; \
} while (0)

  int gx0 = g4 ^ (lr & 7);
  int aro = lr * 64;                       // + mi*1024 + gx*8
  int bro = 8192 + (wc * 64 + lr) * 64;    // + ni*1024 + gx*8

  f32x4 acc[4][4] = {};
  float4 fa0, fa1, fa2, fa3;

  LOADA(0);
  STAGE_B(0);
  asm volatile("s_waitcnt vmcnt(0)" ::: "memory");
  WRITEA(0);
  asm volatile("s_waitcnt lgkmcnt(0)" ::: "memory");
  PHASE_BAR();

  int curA = 0;
  for (int T = 0; T < NKT; ++T) {
    int nxtA = 4096 - curA;
    bool pf = (T < NKT - 1);
    int ktu = (T + 1) * 64;
    bf16x8 b0[4], a0[4];
#pragma unroll
    for (int ni = 0; ni < 4; ++ni) b0[ni] = *(const bf16x8*)(&sm[bro + ni * 1024 + gx0 * 8]);
#pragma unroll
    for (int mi = 0; mi < 4; ++mi) a0[mi] = *(const bf16x8*)(&sm[curA + aro + mi * 1024 + gx0 * 8]);
    __builtin_amdgcn_s_setprio(1);
#pragma unroll
    for (int mi = 0; mi < 4; ++mi)
#pragma unroll
      for (int ni = 0; ni < 4; ++ni)
        acc[mi][ni] = __builtin_amdgcn_mfma_f32_16x16x32_bf16(a0[mi], b0[ni], acc[mi][ni], 0, 0, 0);
    __builtin_amdgcn_s_setprio(0);
    int gx1 = gx0 ^ 4;
    bf16x8 b1[4];
#pragma unroll
    for (int ni = 0; ni < 4; ++ni) b1[ni] = *(const bf16x8*)(&sm[bro + ni * 1024 + gx1 * 8]);
    LGKM0();
    PHASE_BAR();                       // every wave's B reads done -> B free
    if (pf) { STAGE_B(ktu); LOADA(ktu); }
    bf16x8 a1[4];
#pragma unroll
    for (int mi = 0; mi < 4; ++mi) a1[mi] = *(const bf16x8*)(&sm[curA + aro + mi * 1024 + gx1 * 8]);
    __builtin_amdgcn_s_setprio(1);
#pragma unroll
    for (int mi = 0; mi < 4; ++mi)
#pragma unroll
      for (int ni = 0; ni < 4; ++ni)
        acc[mi][ni] = __builtin_amdgcn_mfma_f32_16x16x32_bf16(a1[mi], b1[ni], acc[mi][ni], 0, 0, 0);
    __builtin_amdgcn_s_setprio(0);
    if (pf) {
      asm volatile("s_waitcnt vmcnt(0)" ::: "memory");
      WRITEA(nxtA);
      asm volatile("s_waitcnt lgkmcnt(0)" ::: "memory");
      PHASE_BAR();
    }
    curA = nxtA;
  }

  // epilogue: bias + phi, fp8 out (HW packed encode, branchless)
#pragma unroll
  for (int mi = 0; mi < 4; ++mi) {
#pragma unroll
    for (int ni = 0; ni < 4; ++ni) {
      int col = bcol0 + wc * 64 + ni * 16 + lr;
      float bb = bias[col];
      float v[4];
#pragma unroll
      for (int i = 0; i < 4; ++i) {
        float x = acc[mi][ni][i] + bb;
        v[i] = (x > 0.0f) ? (x + 1.0f) : __expf(x);
      }
      u32 w = enc4fp8(v[0], v[1], v[2], v[3]);
      size_t r0 = arow0 + mi * 16 + g4 * 4;
      C[(r0 + 0) * TD2 + col] = (u8)w;
      C[(r0 + 1) * TD2 + col] = (u8)(w >> 8);
      C[(r0 + 2) * TD2 + col] = (u8)(w >> 16);
      C[(r0 + 3) * TD2 + col] = (u8)(w >> 24);
    }
  }
#undef STAGE_B
#undef LOADA
#undef WRITEA
}

// ---------------------------------------------------------------------------
// Attention qk-phases: one block per (b,h). QK fp8; staging decodes via HW
// cvt into bf16 LDS. Phases = round-17 structure (wave-parallel z/qt).
#define ALD 200

__global__ __launch_bounds__(256) void k_attn_qk(
    const u8* __restrict__ qk,    // [M_,1536] fp8 (phi applied)
    float* __restrict__ AT,       // [B_,4,SP]
    float* __restrict__ AI,       // [B_,4,SP]
    float* __restrict__ sat)      // [4096,4]
{
  __shared__ u16 qs[S_ * ALD];
  __shared__ u16 ks[S_ * ALD];
  __shared__ float z[DH_], qt[DH_], qi[DH_], wt[S_], wi[S_];
  __shared__ float zp[4][DH_];
  __shared__ float qp[4][DH_], qip[4][DH_];
  __shared__ float at_l[S_ + 1], ai_l[S_ + 1];
  int t = threadIdx.x;
  int b = blockIdx.x >> 2, h = blockIdx.x & 3;
  size_t base = (size_t)b * S_ * TD2;
  int qoff = h * DH_, koff = 768 + h * DH_;
  int grp = t >> 4, gl = t & 15;
  int w = t >> 6, ln = t & 63;

  // stage q,k: 16-byte fp8 chunks -> 16 bf16 (32B) per chunk
  for (int idx = t; idx < S_ * 12; idx += 256) {
    int s = idx / 12, c = (idx % 12) * 16;
    size_t gb = base + (size_t)s * TD2;
    uint4 rq = *(const uint4*)(&qk[gb + qoff + c]);
    uint4 rk = *(const uint4*)(&qk[gb + koff + c]);
    uint4 q0, q1, k0, k1;
    dec4(rq.x, q0.x, q0.y); dec4(rq.y, q0.z, q0.w);
    dec4(rq.z, q1.x, q1.y); dec4(rq.w, q1.z, q1.w);
    dec4(rk.x, k0.x, k0.y); dec4(rk.y, k0.z, k0.w);
    dec4(rk.z, k1.x, k1.y); dec4(rk.w, k1.z, k1.w);
    *(uint4*)(&qs[s * ALD + c]) = q0;
    *(uint4*)(&qs[s * ALD + c + 8]) = q1;
    *(uint4*)(&ks[s * ALD + c]) = k0;
    *(uint4*)(&ks[s * ALD + c + 8]) = k1;
  }
  __syncthreads();
  // z[d] = sum_s k[s,d] — wave-parallel partials
  {
    int s0 = w * 18, s1 = (w == 3) ? S_ : (s0 + 18);
    float p0 = 0, p1 = 0, p2 = 0;
    for (int s = s0; s < s1; ++s) {
      p0 += bf2f(ks[s * ALD + ln]);
      p1 += bf2f(ks[s * ALD + ln + 64]);
      p2 += bf2f(ks[s * ALD + ln + 128]);
    }
    zp[w][ln] = p0; zp[w][ln + 64] = p1; zp[w][ln + 128] = p2;
  }
  __syncthreads();
  if (t < DH_) z[t] = (zp[0][t] + zp[1][t]) + (zp[2][t] + zp[3][t]);
  __syncthreads();
  // den[s] = q[s,:].z — 16-lane-group parallel
  for (int s = grp; s < S_; s += 16) {
    float a = 0;
    int d0 = gl * 12;
#pragma unroll
    for (int i = 0; i < 12; ++i) a += bf2f(qs[s * ALD + d0 + i]) * z[d0 + i];
#pragma unroll
    for (int o = 8; o >= 1; o >>= 1) a += __shfl_xor(a, o);
    if (gl == 0) {
      float den = a + 1e-6f;
      wt[s] = (s < TEXT_) ? 1.0f / (35.0f * den) : 0.0f;
      wi[s] = (s >= TEXT_) ? 1.0f / (36.0f * den) : 0.0f;
    }
  }
  __syncthreads();
  // qt[d], qi[d] — wave-parallel partials
  {
    int s0 = w * 18, s1 = (w == 3) ? S_ : (s0 + 18);
    float pt0 = 0, pt1 = 0, pt2 = 0, pi0 = 0, pi1 = 0, pi2 = 0;
    for (int s = s0; s < s1; ++s) {
      float wts = wt[s], wis = wi[s];
      float q0 = bf2f(qs[s * ALD + ln]);
      float q1 = bf2f(qs[s * ALD + ln + 64]);
      float q2 = bf2f(qs[s * ALD + ln + 128]);
      pt0 += q0 * wts; pt1 += q1 * wts; pt2 += q2 * wts;
      pi0 += q0 * wis; pi1 += q1 * wis; pi2 += q2 * wis;
    }
    qp[w][ln] = pt0; qp[w][ln + 64] = pt1; qp[w][ln + 128] = pt2;
    qip[w][ln] = pi0; qip[w][ln + 64] = pi1; qip[w][ln + 128] = pi2;
  }
  __syncthreads();
  if (t < DH_) {
    qt[t] = (qp[0][t] + qp[1][t]) + (qp[2][t] + qp[3][t]);
    qi[t] = (qip[0][t] + qip[1][t]) + (qip[2][t] + qip[3][t]);
  }
  __syncthreads();
  // at[s], ai[s] — group parallel
  size_t arow = ((size_t)b * 4 + h) * SP;
  for (int s = grp; s < S_; s += 16) {
    float aT = 0, aI = 0;
    int d0 = gl * 12;
#pragma unroll
    for (int i = 0; i < 12; ++i) {
      float kv = bf2f(ks[s * ALD + d0 + i]);
      aT += kv * qt[d0 + i]; aI += kv * qi[d0 + i];
    }
#pragma unroll
    for (int o = 8; o >= 1; o >>= 1) { aT += __shfl_xor(aT, o); aI += __shfl_xor(aI, o); }
    if (gl == 0) {
      at_l[s] = aT; ai_l[s] = aI;
      AT[arow + s] = aT; AI[arow + s] = aI;
    }
  }
  __syncthreads();
  if (t < 64) {
    float vT = at_l[t] + ((t < 7) ? at_l[t + 64] : 0.0f);
    float vI = ai_l[t] + ((t < 7) ? ai_l[t + 64] : 0.0f);
#pragma unroll
    for (int o = 32; o >= 1; o >>= 1) { vT += __shfl_xor(vT, o); vI += __shfl_xor(vI, o); }
    if (t == 0) {
      sat[(size_t)b * 4 + h] = vT;
      sat[(size_t)(2048 + b) * 4 + h] = vI;
    }
  }
}

// ---------------------------------------------------------------------------
// Y accumulation: block per b, 192 threads; streams x once (float4).
__global__ __launch_bounds__(192) void k_accy(
    const float* __restrict__ x,  // [B_,71,768] fp32
    const float* __restrict__ AT, // [B_,4,SP]
    const float* __restrict__ AI,
    u16* __restrict__ Y)          // [4096,3072] bf16
{
  __shared__ float at_s[4][S_], ai_s[4][S_];
  int t = threadIdx.x, b = blockIdx.x;
  for (int i = t; i < 4 * S_; i += 192) {
    int h = i / S_, s = i % S_;
    at_s[h][s] = AT[((size_t)b * 4 + h) * SP + s];
    ai_s[h][s] = AI[((size_t)b * 4 + h) * SP + s];
  }
  __syncthreads();
  float4 yt[4] = {}, yi[4] = {};
  const float4* xb = (const float4*)(x + (size_t)b * S_ * 768);
  for (int s = 0; s < S_; ++s) {
    float4 xv = xb[s * 192 + t];
#pragma unroll
    for (int h = 0; h < 4; ++h) {
      float a = at_s[h][s], ai_ = ai_s[h][s];
      yt[h].x += a * xv.x; yt[h].y += a * xv.y; yt[h].z += a * xv.z; yt[h].w += a * xv.w;
      yi[h].x += ai_ * xv.x; yi[h].y += ai_ * xv.y; yi[h].z += ai_ * xv.z; yi[h].w += ai_ * xv.w;
    }
  }
  size_t rt = (size_t)b * 3072, ri = (size_t)(2048 + b) * 3072;
#pragma unroll
  for (int h = 0; h < 4; ++h) {
    uint2 ot, oi;
    ot.x = pk2bf(yt[h].x, yt[h].y); ot.y = pk2bf(yt[h].z, yt[h].w);
    oi.x = pk2bf(yi[h].x, yi[h].y); oi.y = pk2bf(yi[h].z, yi[h].w);
    *(uint2*)(&Y[rt + h * 768 + t * 4]) = ot;
    *(uint2*)(&Y[ri + h * 768 + t * 4]) = oi;
  }
}

// ---------------------------------------------------------------------------
// Grouped v-GEMM: G[4096][768] = Y_h * Wv_h^T + sat*bv (per head h).
__global__ __launch_bounds__(256, 4) void k_gemm_v(
    const u16* __restrict__ Yb,    // [4096,3072] bf16
    const u16* __restrict__ Wbf,   // [2304,768] bf16 (rows 1536+ = Wv)
    const float* __restrict__ bqkv,
    const float* __restrict__ sat, // [4096,4]
    u16* __restrict__ G)           // [4096,768] bf16
{
  __shared__ u16 sm[24576];
  int t = threadIdx.x;
  int lane = t & 63, wid = t >> 6;
  int wr = wid >> 1, wc = wid & 1;
  int lr = lane & 15, g4 = lane >> 4;
  int bm = blockIdx.x / 12, nt = blockIdx.x % 12;
  int h = nt / 3, e0 = (nt % 3) * 64;
  const size_t arow0 = (size_t)bm * 128;

  const u16* srcA[4];
  int dA[4];
#pragma unroll
  for (int j = 0; j < 4; ++j) {
    int c = j * 256 + t;
    int row = c >> 3, kg = (c & 7) ^ (row & 7);
    srcA[j] = Yb + (arow0 + row) * 3072 + h * 768 + kg * 8;
    dA[j] = c * 8;
  }
  const u16* srcB[2];
  int dB[2];
#pragma unroll
  for (int j = 0; j < 2; ++j) {
    int c = j * 256 + t;
    int row = c >> 3, kg = (c & 7) ^ (row & 7);
    srcB[j] = Wbf + (size_t)(1536 + h * DH_ + e0 + row) * 768 + kg * 8;
    dB[j] = c * 8;
  }

#define VSTAGE(abuf, bbuf, ktu) do { \
  gload16(srcA[0] + (ktu), &sm[(abuf) + dA[0]]); \
  gload16(srcA[1] + (ktu), &sm[(abuf) + dA[1]]); \
  gload16(srcA[2] + (ktu), &sm[(abuf) + dA[2]]); \
  gload16(srcA[3] + (ktu), &sm[(abuf) + dA[3]]); \
  gload16(srcB[0] + (ktu), &sm[(bbuf) + dB[0]]); \
  gload16(srcB[1] + (ktu), &sm[(bbuf) + dB[1]]); \
} while (0)

  int gx0 = g4 ^ (lr & 7);
  int aro = (wr * 64 + lr) * 64;
  int bro = (wc * 32 + lr) * 64;

  f32x4 acc[4][2] = {};

  VSTAGE(0, 16384, 0);
  asm volatile("s_waitcnt vmcnt(0)" ::: "memory");
  PHASE_BAR();

  for (int T = 0; T < NKT; ++T) {
    int abuf = (T & 1) * 8192, bbuf = 16384 + (T & 1) * 4096;
    bool pf = (T < NKT - 1);
    if (pf) VSTAGE(8192 - abuf, 20480 - (T & 1) * 4096, (T + 1) * 64);
#pragma unroll
    for (int kk = 0; kk < 2; ++kk) {
      int gx = gx0 ^ (kk * 4);
      bf16x8 a[4], bfr[2];
#pragma unroll
      for (int mi = 0; mi < 4; ++mi) a[mi] = *(const bf16x8*)(&sm[abuf + aro + mi * 1024 + gx * 8]);
#pragma unroll
      for (int ni = 0; ni < 2; ++ni) bfr[ni] = *(const bf16x8*)(&sm[bbuf + bro + ni * 1024 + gx * 8]);
#pragma unroll
      for (int mi = 0; mi < 4; ++mi)
#pragma unroll
        for (int ni = 0; ni < 2; ++ni)
          acc[mi][ni] = __builtin_amdgcn_mfma_f32_16x16x32_bf16(a[mi], bfr[ni], acc[mi][ni], 0, 0, 0);
    }
    if (pf) {
      asm volatile("s_waitcnt vmcnt(0)" ::: "memory");
      PHASE_BAR();
    }
  }

#pragma unroll
  for (int mi = 0; mi < 4; ++mi) {
#pragma unroll
    for (int ni = 0; ni < 2; ++ni) {
      int e = e0 + wc * 32 + ni * 16 + lr;
      int gcol = h * DH_ + e;
      float bv = bqkv[1536 + gcol];
#pragma unroll
      for (int i = 0; i < 4; ++i) {
        size_t row = arow0 + wr * 64 + mi * 16 + g4 * 4 + i;
        G[row * 768 + gcol] = f2bf(acc[mi][ni][i] + sat[row * 4 + h] * bv);
      }
    }
  }
#undef VSTAGE
}

// ---------------------------------------------------------------------------
// Head GEMM: F = tanh(G * w_out^T + b_out)
__global__ __launch_bounds__(512, 4) void k_gemm_head(
    const u16* __restrict__ Gb,   // [4096,768] bf16
    const u16* __restrict__ Wo,   // [768,768] bf16 (n-major)
    const float* __restrict__ bout,
    u16* __restrict__ F)          // [4096,768] bf16
{
  __shared__ u16 sm[32768];
  int t = threadIdx.x;
  int lane = t & 63, wid = t >> 6;
  int wr = wid >> 2, wc = wid & 3;
  int lr = lane & 15;
  int g4 = lane >> 4;

  int bm = blockIdx.x / 3, bn = blockIdx.x % 3;
  const size_t arow0 = (size_t)bm * 128;
  const int bcol0 = bn * 256;

  const u16* srcA[2];
  int dA[2];
#pragma unroll
  for (int j = 0; j < 2; ++j) {
    int c = j * 512 + t;
    srcA[j] = Gb + (arow0 + (c >> 3)) * 768 + ((c & 7) ^ ((c >> 3) & 7)) * 8;
    dA[j] = c * 8;
  }
  const u16* srcB[4];
  int dB[4];
#pragma unroll
  for (int j = 0; j < 4; ++j) {
    int c = j * 512 + t;
    srcB[j] = Wo + (size_t)(bcol0 + (c >> 3)) * 768 + ((c & 7) ^ ((c >> 3) & 7)) * 8;
    dB[j] = 16384 + c * 8;
  }

#define STAGE_A2(abuf, ktu) do { \
  gload16(srcA[0] + (ktu), &sm[(abuf) + dA[0]]); \
  gload16(srcA[1] + (ktu), &sm[(abuf) + dA[1]]); \
} while (0)
#define STAGE_B2(ktu) do { \
  gload16(srcB[0] + (ktu), &sm[dB[0]]); \
  gload16(srcB[1] + (ktu), &sm[dB[1]]); \
  gload16(srcB[2] + (ktu), &sm[dB[2]]); \
  gload16(srcB[3] + (ktu), &sm[dB[3]]); \
} while (0)

  int gx0 = g4 ^ (lr & 7);
  int aro = (wr * 64 + lr) * 64;
  int bro = 16384 + (wc * 64 + lr) * 64;

  f32x4 acc[4][4] = {};

  STAGE_A2(0, 0); STAGE_B2(0);
  asm volatile("s_waitcnt vmcnt(0)" ::: "memory");
  PHASE_BAR();

  int curA = 0;
  for (int T = 0; T < NKT; ++T) {
    int nxtA = 8192 - curA;
    bool pf = (T < NKT - 1);
    int ktu = (T + 1) * 64;
    bf16x8 bfr[4][2];
#pragma unroll
    for (int ni = 0; ni < 4; ++ni) {
      bfr[ni][0] = *(const bf16x8*)(&sm[bro + ni * 1024 + gx0 * 8]);
      bfr[ni][1] = *(const bf16x8*)(&sm[bro + ni * 1024 + (gx0 ^ 4) * 8]);
    }
    LGKM0();
    PHASE_BAR();
    if (pf) { STAGE_B2(ktu); STAGE_A2(nxtA, ktu); }
    __builtin_amdgcn_s_setprio(1);
#pragma unroll
    for (int kk = 0; kk < 2; ++kk) {
      int gx = gx0 ^ (kk * 4);
      bf16x8 afr[4];
#pragma unroll
      for (int mi = 0; mi < 4; ++mi)
        afr[mi] = *(const bf16x8*)(&sm[curA + aro + mi * 1024 + gx * 8]);
#pragma unroll
      for (int mi = 0; mi < 4; ++mi)
#pragma unroll
        for (int ni = 0; ni < 4; ++ni)
          acc[mi][ni] = __builtin_amdgcn_mfma_f32_16x16x32_bf16(afr[mi], bfr[ni][kk], acc[mi][ni], 0, 0, 0);
    }
    __builtin_amdgcn_s_setprio(0);
    if (pf) {
      asm volatile("s_waitcnt vmcnt(0)" ::: "memory");
      PHASE_BAR();
    }
    curA = nxtA;
  }

#pragma unroll
  for (int mi = 0; mi < 4; ++mi) {
#pragma unroll
    for (int ni = 0; ni < 4; ++ni) {
      int col = bcol0 + wc * 64 + ni * 16 + lr;
      float bb = bout[col];
#pragma unroll
      for (int i = 0; i < 4; ++i) {
        size_t row = arow0 + wr * 64 + mi * 16 + g4 * 4 + i;
        F[row * 768 + col] = f2bf(tanhf(acc[mi][ni][i] + bb));
      }
    }
  }
#undef STAGE_A2
#undef STAGE_B2
}

// ---------------------------------------------------------------------------
#define GC 4
__global__ __launch_bounds__(256) void k_cos(
    const u16* __restrict__ F,    // [4096,768] bf16 (tanh applied)
    float* __restrict__ out)      // [B_]
{
  __shared__ float red[3][4];
  int t = threadIdx.x, b0 = blockIdx.x * GC;
  int lane = t & 63, wid = t >> 6;
  for (int g = 0; g < GC; ++g) {
    int b = b0 + g;
    float st = 0, si = 0, sd = 0;
#pragma unroll
    for (int j = 0; j < 3; ++j) {
      int c = t + j * 256;
      float rt = bf2f(F[(size_t)b * 768 + c]);
      float ri = bf2f(F[(size_t)(2048 + b) * 768 + c]);
      st += rt * rt; si += ri * ri; sd += rt * ri;
    }
#pragma unroll
    for (int off = 32; off >= 1; off >>= 1) {
      st += __shfl_down(st, off);
      si += __shfl_down(si, off);
      sd += __shfl_down(sd, off);
    }
    __syncthreads();
    if (lane == 0) { red[0][wid] = st; red[1][wid] = si; red[2][wid] = sd; }
    __syncthreads();
    if (t == 0) {
      float S1 = red[0][0] + red[0][1] + red[0][2] + red[0][3];
      float S2 = red[1][0] + red[1][1] + red[1][2] + red[1][3];
      float S3 = red[2][0] + red[2][1] + red[2][2] + red[2][3];
      out[b] = S3 / (fmaxf(sqrtf(S1), 1e-8f) * fmaxf(sqrtf(S2), 1e-8f));
    }
  }
}

// ---------------------------------------------------------------------------
extern "C" void kernel_launch(void* const* d_in, const int* in_sizes, int n_in,
                              void* d_out, int out_size, void* d_ws, size_t ws_size,
                              hipStream_t stream) {
  const float* features = (const float*)d_in[0];
  // d_in[1] = attention_mask (unused by forward)
  const float* w_qkv = (const float*)d_in[2];
  const float* b_qkv = (const float*)d_in[3];
  const float* w_out = (const float*)d_in[4];
  const float* b_out = (const float*)d_in[5];
  float* out = (float*)d_out;

  char* ws = (char*)d_ws;
  size_t off = 0;
  auto alloc = [&](size_t bytes) {
    void* p = ws + off;
    off += (bytes + 255) & ~(size_t)255;
    return p;
  };
  u8*  QK   = (u8*)alloc((size_t)M_ * TD2);          // 218 MB (fp8)
  u16* Wbf  = (u16*)alloc((size_t)2304 * D_ * 2);    // 3.5 MB
  u16* Wobf = (u16*)alloc((size_t)D_ * D_ * 2);      // 1.2 MB
  u16* Yv   = (u16*)alloc((size_t)4096 * 3072 * 2);  // 25 MB
  float* AT = (float*)alloc((size_t)B_ * 4 * SP * 4); // 2.4 MB
  float* AI = (float*)alloc((size_t)B_ * 4 * SP * 4); // 2.4 MB
  float* sat = (float*)alloc((size_t)4096 * 4 * 4);  // 64 KB
  u16* G    = (u16*)alloc((size_t)4096 * D_ * 2);    // 6.3 MB
  u16* F    = (u16*)alloc((size_t)4096 * D_ * 2);    // 6.3 MB
  (void)ws_size;

  hipLaunchKernelGGL(k_cvt_bf16, dim3((2304 * D_ / 8 + 255) / 256), dim3(256), 0, stream,
                     w_qkv, Wbf, 2304 * D_ / 8);
  hipLaunchKernelGGL(k_cvt_bf16, dim3((D_ * D_ / 8 + 255) / 256), dim3(256), 0, stream,
                     w_out, Wobf, D_ * D_ / 8);

  hipLaunchKernelGGL(k_gemm_qkv, dim3(2272 * 6), dim3(256), 0, stream,
                     features, Wbf, b_qkv, QK);
  hipLaunchKernelGGL(k_attn_qk, dim3(B_ * H_), dim3(256), 0, stream, QK, AT, AI, sat);
  hipLaunchKernelGGL(k_accy, dim3(B_), dim3(192), 0, stream, features, AT, AI, Yv);
  hipLaunchKernelGGL(k_gemm_v, dim3(32 * 12), dim3(256), 0, stream,
                     Yv, Wbf, b_qkv, sat, G);
  hipLaunchKernelGGL(k_gemm_head, dim3(32 * 3), dim3(512), 0, stream,
                     G, Wobf, b_out, F);
  hipLaunchKernelGGL(k_cos, dim3(B_ / GC), dim3(256), 0, stream, F, out);
}

// Round 20
// 710.962 us; speedup vs baseline: 1.1841x; 1.1055x over previous
//
#include <hip/hip_runtime.h>
#include <hip/hip_bf16.h>

#define B_ 2048
#define S_ 71
#define SP 72               // padded stride for at/ai
#define D_ 768
#define H_ 4
#define DH_ 192
#define TD2 1536            // q,k only
#define M_ (B_ * S_)        // 145408 = 1136*128
#define TEXT_ 35
#define NKT 12              // 768 / 64 K-tiles

typedef unsigned short u16;
typedef unsigned char u8;
typedef unsigned int u32;
typedef __attribute__((ext_vector_type(2))) float f32x2;
typedef __attribute__((ext_vector_type(4))) float f32x4;
typedef __attribute__((ext_vector_type(8))) short bf16x8;

__device__ __forceinline__ u16 f2bf(float f) {
  u32 u = __float_as_uint(f);
  u32 r = (u + 0x7FFFu + ((u >> 16) & 1u)) >> 16;  // RNE
  return (u16)r;
}
__device__ __forceinline__ float bf2f(u16 x) {
  return __uint_as_float(((u32)x) << 16);
}
__device__ __forceinline__ u32 pk2bf(float lo, float hi) {
  __hip_bfloat162 h = __float22bfloat162_rn(float2{lo, hi});
  return *reinterpret_cast<u32*>(&h);
}

// ---- fp8 e4m3 codec: HW single-instruction path (gfx940+), guarded -------
#if __has_builtin(__builtin_amdgcn_cvt_pk_fp8_f32) && __has_builtin(__builtin_amdgcn_cvt_pk_f32_fp8)
__device__ __forceinline__ u32 enc4fp8(float a, float b, float c, float d) {
  int w = 0;
  w = __builtin_amdgcn_cvt_pk_fp8_f32(a, b, w, false);
  w = __builtin_amdgcn_cvt_pk_fp8_f32(c, d, w, true);
  return (u32)w;
}
__device__ __forceinline__ void dec4(u32 w, u32& lo, u32& hi) {
  f32x2 a = __builtin_amdgcn_cvt_pk_f32_fp8((int)w, false);
  f32x2 b = __builtin_amdgcn_cvt_pk_f32_fp8((int)w, true);
  lo = pk2bf(a.x, a.y);
  hi = pk2bf(b.x, b.y);
}
#else
// branchless fallback (positive inputs)
__device__ __forceinline__ u8 f2fp8_1(float f) {
  f = fminf(f, 448.0f);
  u32 u = __float_as_uint(f);
  int e = (int)((u >> 23) & 0xFF) - 127;
  u32 m = u & 0x7FFFFF;
  u32 keep = m >> 20, rest = m & 0xFFFFF;
  u32 rb = (rest > 0x80000u) || (rest == 0x80000u && (keep & 1));
  u32 nrm = (((u32)(e + 7)) << 3) + keep + rb;
  u32 sub = (u32)__float2int_rn(f * 512.0f);
  u32 r = (e >= -6) ? nrm : ((e < -10) ? 0u : sub);
  return (u8)r;
}
__device__ __forceinline__ u32 enc4fp8(float a, float b, float c, float d) {
  return (u32)f2fp8_1(a) | ((u32)f2fp8_1(b) << 8) | ((u32)f2fp8_1(c) << 16) | ((u32)f2fp8_1(d) << 24);
}
__device__ __forceinline__ float fp82f(u32 v) {
  u32 e = (v >> 3) & 0xF, m = v & 7;
  float nrm = __uint_as_float(((e + 120) << 23) | (m << 20));
  return e ? nrm : (float)m * 0.001953125f;
}
__device__ __forceinline__ void dec4(u32 w, u32& lo, u32& hi) {
  lo = pk2bf(fp82f(w & 0xFF), fp82f((w >> 8) & 0xFF));
  hi = pk2bf(fp82f((w >> 16) & 0xFF), fp82f(w >> 24));
}
#endif

typedef __attribute__((address_space(1))) const unsigned int GASU;
typedef __attribute__((address_space(3))) unsigned int LASU;
__device__ __forceinline__ void gload16(const void* g, void* l) {
  __builtin_amdgcn_global_load_lds((GASU*)g, (LASU*)l, 16, 0, 0);
}

#define PHASE_BAR() do { __builtin_amdgcn_s_barrier(); asm volatile("" ::: "memory"); } while (0)
#define LGKM0() do { asm volatile("s_waitcnt lgkmcnt(0)" ::: "memory"); __builtin_amdgcn_sched_barrier(0); } while (0)

// ---------------------------------------------------------------------------
__global__ __launch_bounds__(256) void k_cvt_bf16(const float* __restrict__ in,
                                                  u16* __restrict__ out, int n8) {
  int idx = blockIdx.x * 256 + threadIdx.x;
  if (idx >= n8) return;
  const float4* p = (const float4*)(in + (size_t)idx * 8);
  float4 a = p[0], b = p[1];
  uint4 o;
  o.x = pk2bf(a.x, a.y);
  o.y = pk2bf(a.z, a.w);
  o.z = pk2bf(b.x, b.y);
  o.w = pk2bf(b.z, b.w);
  *(uint4*)(out + (size_t)idx * 8) = o;
}

// ---------------------------------------------------------------------------
// Main GEMM — q,k only: C[M,1536] = phi(A(fp32)*Wqk^T + bias), fp8 out via
// HW codec. PROVEN geometry (r17): 128x256 tile, BK=64, 8 waves, A reg-staged
// dbuf + B gload_lds, 64KB LDS, launch_bounds(512,4) -> 16 waves/CU.
// (r19's 64x256 "3 blocks/CU" retile was 12 waves/CU — occupancy loss.)
__global__ __launch_bounds__(512, 4) void k_gemm_qkv(
    const float* __restrict__ Afp,  // [M_,768] fp32 (features)
    const u16* __restrict__ Bw,     // [2304,768] bf16 (rows 0..1535 used)
    const float* __restrict__ bias, // [2304]
    u8* __restrict__ C)             // [M_,1536] fp8, phi everywhere
{
  __shared__ u16 sm[32768];   // 64 KiB
  int t = threadIdx.x;
  int lane = t & 63, wid = t >> 6;
  int wr = wid >> 2, wc = wid & 3;
  int lr = lane & 15;
  int g4 = lane >> 4;

  // XCD-bijective swizzle: nwg = 6816 = 8*852
  int swz = (blockIdx.x & 7) * 852 + (blockIdx.x >> 3);
  int bm = swz / 6, bn = swz % 6;
  const size_t arow0 = (size_t)bm * 128;
  const int bcol0 = bn * 256;

  const float* srcAf[2];
  int dA[2];
#pragma unroll
  for (int j = 0; j < 2; ++j) {
    int c = j * 512 + t;
    srcAf[j] = Afp + (arow0 + (c >> 3)) * 768 + ((c & 7) ^ ((c >> 3) & 7)) * 8;
    dA[j] = c * 8;
  }
  const u16* srcB[4];
  int dB[4];
#pragma unroll
  for (int j = 0; j < 4; ++j) {
    int c = j * 512 + t;
    srcB[j] = Bw + (size_t)(bcol0 + (c >> 3)) * 768 + ((c & 7) ^ ((c >> 3) & 7)) * 8;
    dB[j] = 16384 + c * 8;
  }

#define STAGE_B(ktu) do { \
  gload16(srcB[0] + (ktu), &sm[dB[0]]); \
  gload16(srcB[1] + (ktu), &sm[dB[1]]); \
  gload16(srcB[2] + (ktu), &sm[dB[2]]); \
  gload16(srcB[3] + (ktu), &sm[dB[3]]); \
} while (0)
#define LOADA(ktu) do { \
  fa0 = *(const float4*)(srcAf[0] + (ktu)); \
  fa1 = *(const float4*)(srcAf[0] + (ktu) + 4); \
  fa2 = *(const float4*)(srcAf[1] + (ktu)); \
  fa3 = *(const float4*)(srcAf[1] + (ktu) + 4); \
} while (0)
#define WRITEA(abuf) do { \
  uint4 o0; \
  o0.x = pk2bf(fa0.x, fa0.y); o0.y = pk2bf(fa0.z, fa0.w); \
  o0.z = pk2bf(fa1.x, fa1.y); o0.w = pk2bf(fa1.z, fa1.w); \
  *(uint4*)(&sm[(abuf) + dA[0]]) = o0; \
  uint4 o1; \
  o1.x = pk2bf(fa2.x, fa2.y); o1.y = pk2bf(fa2.z, fa2.w); \
  o1.z = pk2bf(fa3.x, fa3.y); o1.w = pk2bf(fa3.z, fa3.w); \
  *(uint4*)(&sm[(abuf) + dA[1]]) = o1; \
} while (0)

  int gx0 = g4 ^ (lr & 7);
  int aro = (wr * 64 + lr) * 64;
  int bro = 16384 + (wc * 64 + lr) * 64;

  f32x4 acc[4][4] = {};
  float4 fa0, fa1, fa2, fa3;

  LOADA(0);
  STAGE_B(0);
  asm volatile("s_waitcnt vmcnt(0)" ::: "memory");
  WRITEA(0);
  asm volatile("s_waitcnt lgkmcnt(0)" ::: "memory");
  PHASE_BAR();

  int curA = 0;
  for (int T = 0; T < NKT; ++T) {
    int nxtA = 8192 - curA;
    bool pf = (T < NKT - 1);
    int ktu = (T + 1) * 64;
    bf16x8 b0[4], a0[4];
#pragma unroll
    for (int ni = 0; ni < 4; ++ni) b0[ni] = *(const bf16x8*)(&sm[bro + ni * 1024 + gx0 * 8]);
#pragma unroll
    for (int mi = 0; mi < 4; ++mi) a0[mi] = *(const bf16x8*)(&sm[curA + aro + mi * 1024 + gx0 * 8]);
    __builtin_amdgcn_s_setprio(1);
#pragma unroll
    for (int mi = 0; mi < 4; ++mi)
#pragma unroll
      for (int ni = 0; ni < 4; ++ni)
        acc[mi][ni] = __builtin_amdgcn_mfma_f32_16x16x32_bf16(a0[mi], b0[ni], acc[mi][ni], 0, 0, 0);
    __builtin_amdgcn_s_setprio(0);
    int gx1 = gx0 ^ 4;
    bf16x8 b1[4];
#pragma unroll
    for (int ni = 0; ni < 4; ++ni) b1[ni] = *(const bf16x8*)(&sm[bro + ni * 1024 + gx1 * 8]);
    LGKM0();
    PHASE_BAR();                       // every wave's B reads done -> B free
    if (pf) { STAGE_B(ktu); LOADA(ktu); }
    bf16x8 a1[4];
#pragma unroll
    for (int mi = 0; mi < 4; ++mi) a1[mi] = *(const bf16x8*)(&sm[curA + aro + mi * 1024 + gx1 * 8]);
    __builtin_amdgcn_s_setprio(1);
#pragma unroll
    for (int mi = 0; mi < 4; ++mi)
#pragma unroll
      for (int ni = 0; ni < 4; ++ni)
        acc[mi][ni] = __builtin_amdgcn_mfma_f32_16x16x32_bf16(a1[mi], b1[ni], acc[mi][ni], 0, 0, 0);
    __builtin_amdgcn_s_setprio(0);
    if (pf) {
      asm volatile("s_waitcnt vmcnt(0)" ::: "memory");
      WRITEA(nxtA);
      asm volatile("s_waitcnt lgkmcnt(0)" ::: "memory");
      PHASE_BAR();
    }
    curA = nxtA;
  }

  // epilogue: bias + phi, fp8 out (HW packed encode, branchless)
#pragma unroll
  for (int mi = 0; mi < 4; ++mi) {
#pragma unroll
    for (int ni = 0; ni < 4; ++ni) {
      int col = bcol0 + wc * 64 + ni * 16 + lr;
      float bb = bias[col];
      float v[4];
#pragma unroll
      for (int i = 0; i < 4; ++i) {
        float x = acc[mi][ni][i] + bb;
        v[i] = (x > 0.0f) ? (x + 1.0f) : __expf(x);
      }
      u32 w = enc4fp8(v[0], v[1], v[2], v[3]);
      size_t r0 = arow0 + wr * 64 + mi * 16 + g4 * 4;
      C[(r0 + 0) * TD2 + col] = (u8)w;
      C[(r0 + 1) * TD2 + col] = (u8)(w >> 8);
      C[(r0 + 2) * TD2 + col] = (u8)(w >> 16);
      C[(r0 + 3) * TD2 + col] = (u8)(w >> 24);
    }
  }
#undef STAGE_B
#undef LOADA
#undef WRITEA
}

// ---------------------------------------------------------------------------
// Attention qk-phases: one block per (b,h). QK fp8; staging decodes via HW
// cvt into bf16 LDS. Phases = round-17 structure (wave-parallel z/qt).
#define ALD 200

__global__ __launch_bounds__(256) void k_attn_qk(
    const u8* __restrict__ qk,    // [M_,1536] fp8 (phi applied)
    float* __restrict__ AT,       // [B_,4,SP]
    float* __restrict__ AI,       // [B_,4,SP]
    float* __restrict__ sat)      // [4096,4]
{
  __shared__ u16 qs[S_ * ALD];
  __shared__ u16 ks[S_ * ALD];
  __shared__ float z[DH_], qt[DH_], qi[DH_], wt[S_], wi[S_];
  __shared__ float zp[4][DH_];
  __shared__ float qp[4][DH_], qip[4][DH_];
  __shared__ float at_l[S_ + 1], ai_l[S_ + 1];
  int t = threadIdx.x;
  int b = blockIdx.x >> 2, h = blockIdx.x & 3;
  size_t base = (size_t)b * S_ * TD2;
  int qoff = h * DH_, koff = 768 + h * DH_;
  int grp = t >> 4, gl = t & 15;
  int w = t >> 6, ln = t & 63;

  // stage q,k: 16-byte fp8 chunks -> 16 bf16 (32B) per chunk
  for (int idx = t; idx < S_ * 12; idx += 256) {
    int s = idx / 12, c = (idx % 12) * 16;
    size_t gb = base + (size_t)s * TD2;
    uint4 rq = *(const uint4*)(&qk[gb + qoff + c]);
    uint4 rk = *(const uint4*)(&qk[gb + koff + c]);
    uint4 q0, q1, k0, k1;
    dec4(rq.x, q0.x, q0.y); dec4(rq.y, q0.z, q0.w);
    dec4(rq.z, q1.x, q1.y); dec4(rq.w, q1.z, q1.w);
    dec4(rk.x, k0.x, k0.y); dec4(rk.y, k0.z, k0.w);
    dec4(rk.z, k1.x, k1.y); dec4(rk.w, k1.z, k1.w);
    *(uint4*)(&qs[s * ALD + c]) = q0;
    *(uint4*)(&qs[s * ALD + c + 8]) = q1;
    *(uint4*)(&ks[s * ALD + c]) = k0;
    *(uint4*)(&ks[s * ALD + c + 8]) = k1;
  }
  __syncthreads();
  // z[d] = sum_s k[s,d] — wave-parallel partials
  {
    int s0 = w * 18, s1 = (w == 3) ? S_ : (s0 + 18);
    float p0 = 0, p1 = 0, p2 = 0;
    for (int s = s0; s < s1; ++s) {
      p0 += bf2f(ks[s * ALD + ln]);
      p1 += bf2f(ks[s * ALD + ln + 64]);
      p2 += bf2f(ks[s * ALD + ln + 128]);
    }
    zp[w][ln] = p0; zp[w][ln + 64] = p1; zp[w][ln + 128] = p2;
  }
  __syncthreads();
  if (t < DH_) z[t] = (zp[0][t] + zp[1][t]) + (zp[2][t] + zp[3][t]);
  __syncthreads();
  // den[s] = q[s,:].z — 16-lane-group parallel
  for (int s = grp; s < S_; s += 16) {
    float a = 0;
    int d0 = gl * 12;
#pragma unroll
    for (int i = 0; i < 12; ++i) a += bf2f(qs[s * ALD + d0 + i]) * z[d0 + i];
#pragma unroll
    for (int o = 8; o >= 1; o >>= 1) a += __shfl_xor(a, o);
    if (gl == 0) {
      float den = a + 1e-6f;
      wt[s] = (s < TEXT_) ? 1.0f / (35.0f * den) : 0.0f;
      wi[s] = (s >= TEXT_) ? 1.0f / (36.0f * den) : 0.0f;
    }
  }
  __syncthreads();
  // qt[d], qi[d] — wave-parallel partials
  {
    int s0 = w * 18, s1 = (w == 3) ? S_ : (s0 + 18);
    float pt0 = 0, pt1 = 0, pt2 = 0, pi0 = 0, pi1 = 0, pi2 = 0;
    for (int s = s0; s < s1; ++s) {
      float wts = wt[s], wis = wi[s];
      float q0 = bf2f(qs[s * ALD + ln]);
      float q1 = bf2f(qs[s * ALD + ln + 64]);
      float q2 = bf2f(qs[s * ALD + ln + 128]);
      pt0 += q0 * wts; pt1 += q1 * wts; pt2 += q2 * wts;
      pi0 += q0 * wis; pi1 += q1 * wis; pi2 += q2 * wis;
    }
    qp[w][ln] = pt0; qp[w][ln + 64] = pt1; qp[w][ln + 128] = pt2;
    qip[w][ln] = pi0; qip[w][ln + 64] = pi1; qip[w][ln + 128] = pi2;
  }
  __syncthreads();
  if (t < DH_) {
    qt[t] = (qp[0][t] + qp[1][t]) + (qp[2][t] + qp[3][t]);
    qi[t] = (qip[0][t] + qip[1][t]) + (qip[2][t] + qip[3][t]);
  }
  __syncthreads();
  // at[s], ai[s] — group parallel
  size_t arow = ((size_t)b * 4 + h) * SP;
  for (int s = grp; s < S_; s += 16) {
    float aT = 0, aI = 0;
    int d0 = gl * 12;
#pragma unroll
    for (int i = 0; i < 12; ++i) {
      float kv = bf2f(ks[s * ALD + d0 + i]);
      aT += kv * qt[d0 + i]; aI += kv * qi[d0 + i];
    }
#pragma unroll
    for (int o = 8; o >= 1; o >>= 1) { aT += __shfl_xor(aT, o); aI += __shfl_xor(aI, o); }
    if (gl == 0) {
      at_l[s] = aT; ai_l[s] = aI;
      AT[arow + s] = aT; AI[arow + s] = aI;
    }
  }
  __syncthreads();
  if (t < 64) {
    float vT = at_l[t] + ((t < 7) ? at_l[t + 64] : 0.0f);
    float vI = ai_l[t] + ((t < 7) ? ai_l[t + 64] : 0.0f);
#pragma unroll
    for (int o = 32; o >= 1; o >>= 1) { vT += __shfl_xor(vT, o); vI += __shfl_xor(vI, o); }
    if (t == 0) {
      sat[(size_t)b * 4 + h] = vT;
      sat[(size_t)(2048 + b) * 4 + h] = vI;
    }
  }
}

// ---------------------------------------------------------------------------
// Y accumulation: block per b, 192 threads; streams x once (float4).
__global__ __launch_bounds__(192) void k_accy(
    const float* __restrict__ x,  // [B_,71,768] fp32
    const float* __restrict__ AT, // [B_,4,SP]
    const float* __restrict__ AI,
    u16* __restrict__ Y)          // [4096,3072] bf16
{
  __shared__ float at_s[4][S_], ai_s[4][S_];
  int t = threadIdx.x, b = blockIdx.x;
  for (int i = t; i < 4 * S_; i += 192) {
    int h = i / S_, s = i % S_;
    at_s[h][s] = AT[((size_t)b * 4 + h) * SP + s];
    ai_s[h][s] = AI[((size_t)b * 4 + h) * SP + s];
  }
  __syncthreads();
  float4 yt[4] = {}, yi[4] = {};
  const float4* xb = (const float4*)(x + (size_t)b * S_ * 768);
  for (int s = 0; s < S_; ++s) {
    float4 xv = xb[s * 192 + t];
#pragma unroll
    for (int h = 0; h < 4; ++h) {
      float a = at_s[h][s], ai_ = ai_s[h][s];
      yt[h].x += a * xv.x; yt[h].y += a * xv.y; yt[h].z += a * xv.z; yt[h].w += a * xv.w;
      yi[h].x += ai_ * xv.x; yi[h].y += ai_ * xv.y; yi[h].z += ai_ * xv.z; yi[h].w += ai_ * xv.w;
    }
  }
  size_t rt = (size_t)b * 3072, ri = (size_t)(2048 + b) * 3072;
#pragma unroll
  for (int h = 0; h < 4; ++h) {
    uint2 ot, oi;
    ot.x = pk2bf(yt[h].x, yt[h].y); ot.y = pk2bf(yt[h].z, yt[h].w);
    oi.x = pk2bf(yi[h].x, yi[h].y); oi.y = pk2bf(yi[h].z, yi[h].w);
    *(uint2*)(&Y[rt + h * 768 + t * 4]) = ot;
    *(uint2*)(&Y[ri + h * 768 + t * 4]) = oi;
  }
}

// ---------------------------------------------------------------------------
// Grouped v-GEMM: G[4096][768] = Y_h * Wv_h^T + sat*bv (per head h).
__global__ __launch_bounds__(256, 4) void k_gemm_v(
    const u16* __restrict__ Yb,    // [4096,3072] bf16
    const u16* __restrict__ Wbf,   // [2304,768] bf16 (rows 1536+ = Wv)
    const float* __restrict__ bqkv,
    const float* __restrict__ sat, // [4096,4]
    u16* __restrict__ G)           // [4096,768] bf16
{
  __shared__ u16 sm[24576];
  int t = threadIdx.x;
  int lane = t & 63, wid = t >> 6;
  int wr = wid >> 1, wc = wid & 1;
  int lr = lane & 15, g4 = lane >> 4;
  int bm = blockIdx.x / 12, nt = blockIdx.x % 12;
  int h = nt / 3, e0 = (nt % 3) * 64;
  const size_t arow0 = (size_t)bm * 128;

  const u16* srcA[4];
  int dA[4];
#pragma unroll
  for (int j = 0; j < 4; ++j) {
    int c = j * 256 + t;
    int row = c >> 3, kg = (c & 7) ^ (row & 7);
    srcA[j] = Yb + (arow0 + row) * 3072 + h * 768 + kg * 8;
    dA[j] = c * 8;
  }
  const u16* srcB[2];
  int dB[2];
#pragma unroll
  for (int j = 0; j < 2; ++j) {
    int c = j * 256 + t;
    int row = c >> 3, kg = (c & 7) ^ (row & 7);
    srcB[j] = Wbf + (size_t)(1536 + h * DH_ + e0 + row) * 768 + kg * 8;
    dB[j] = c * 8;
  }

#define VSTAGE(abuf, bbuf, ktu) do { \
  gload16(srcA[0] + (ktu), &sm[(abuf) + dA[0]]); \
  gload16(srcA[1] + (ktu), &sm[(abuf) + dA[1]]); \
  gload16(srcA[2] + (ktu), &sm[(abuf) + dA[2]]); \
  gload16(srcA[3] + (ktu), &sm[(abuf) + dA[3]]); \
  gload16(srcB[0] + (ktu), &sm[(bbuf) + dB[0]]); \
  gload16(srcB[1] + (ktu), &sm[(bbuf) + dB[1]]); \
} while (0)

  int gx0 = g4 ^ (lr & 7);
  int aro = (wr * 64 + lr) * 64;
  int bro = (wc * 32 + lr) * 64;

  f32x4 acc[4][2] = {};

  VSTAGE(0, 16384, 0);
  asm volatile("s_waitcnt vmcnt(0)" ::: "memory");
  PHASE_BAR();

  for (int T = 0; T < NKT; ++T) {
    int abuf = (T & 1) * 8192, bbuf = 16384 + (T & 1) * 4096;
    bool pf = (T < NKT - 1);
    if (pf) VSTAGE(8192 - abuf, 20480 - (T & 1) * 4096, (T + 1) * 64);
#pragma unroll
    for (int kk = 0; kk < 2; ++kk) {
      int gx = gx0 ^ (kk * 4);
      bf16x8 a[4], bfr[2];
#pragma unroll
      for (int mi = 0; mi < 4; ++mi) a[mi] = *(const bf16x8*)(&sm[abuf + aro + mi * 1024 + gx * 8]);
#pragma unroll
      for (int ni = 0; ni < 2; ++ni) bfr[ni] = *(const bf16x8*)(&sm[bbuf + bro + ni * 1024 + gx * 8]);
#pragma unroll
      for (int mi = 0; mi < 4; ++mi)
#pragma unroll
        for (int ni = 0; ni < 2; ++ni)
          acc[mi][ni] = __builtin_amdgcn_mfma_f32_16x16x32_bf16(a[mi], bfr[ni], acc[mi][ni], 0, 0, 0);
    }
    if (pf) {
      asm volatile("s_waitcnt vmcnt(0)" ::: "memory");
      PHASE_BAR();
    }
  }

#pragma unroll
  for (int mi = 0; mi < 4; ++mi) {
#pragma unroll
    for (int ni = 0; ni < 2; ++ni) {
      int e = e0 + wc * 32 + ni * 16 + lr;
      int gcol = h * DH_ + e;
      float bv = bqkv[1536 + gcol];
#pragma unroll
      for (int i = 0; i < 4; ++i) {
        size_t row = arow0 + wr * 64 + mi * 16 + g4 * 4 + i;
        G[row * 768 + gcol] = f2bf(acc[mi][ni][i] + sat[row * 4 + h] * bv);
      }
    }
  }
#undef VSTAGE
}

// ---------------------------------------------------------------------------
// Head GEMM: F = tanh(G * w_out^T + b_out)
__global__ __launch_bounds__(512, 4) void k_gemm_head(
    const u16* __restrict__ Gb,   // [4096,768] bf16
    const u16* __restrict__ Wo,   // [768,768] bf16 (n-major)
    const float* __restrict__ bout,
    u16* __restrict__ F)          // [4096,768] bf16
{
  __shared__ u16 sm[32768];
  int t = threadIdx.x;
  int lane = t & 63, wid = t >> 6;
  int wr = wid >> 2, wc = wid & 3;
  int lr = lane & 15;
  int g4 = lane >> 4;

  int bm = blockIdx.x / 3, bn = blockIdx.x % 3;
  const size_t arow0 = (size_t)bm * 128;
  const int bcol0 = bn * 256;

  const u16* srcA[2];
  int dA[2];
#pragma unroll
  for (int j = 0; j < 2; ++j) {
    int c = j * 512 + t;
    srcA[j] = Gb + (arow0 + (c >> 3)) * 768 + ((c & 7) ^ ((c >> 3) & 7)) * 8;
    dA[j] = c * 8;
  }
  const u16* srcB[4];
  int dB[4];
#pragma unroll
  for (int j = 0; j < 4; ++j) {
    int c = j * 512 + t;
    srcB[j] = Wo + (size_t)(bcol0 + (c >> 3)) * 768 + ((c & 7) ^ ((c >> 3) & 7)) * 8;
    dB[j] = 16384 + c * 8;
  }

#define STAGE_A2(abuf, ktu) do { \
  gload16(srcA[0] + (ktu), &sm[(abuf) + dA[0]]); \
  gload16(srcA[1] + (ktu), &sm[(abuf) + dA[1]]); \
} while (0)
#define STAGE_B2(ktu) do { \
  gload16(srcB[0] + (ktu), &sm[dB[0]]); \
  gload16(srcB[1] + (ktu), &sm[dB[1]]); \
  gload16(srcB[2] + (ktu), &sm[dB[2]]); \
  gload16(srcB[3] + (ktu), &sm[dB[3]]); \
} while (0)

  int gx0 = g4 ^ (lr & 7);
  int aro = (wr * 64 + lr) * 64;
  int bro = 16384 + (wc * 64 + lr) * 64;

  f32x4 acc[4][4] = {};

  STAGE_A2(0, 0); STAGE_B2(0);
  asm volatile("s_waitcnt vmcnt(0)" ::: "memory");
  PHASE_BAR();

  int curA = 0;
  for (int T = 0; T < NKT; ++T) {
    int nxtA = 8192 - curA;
    bool pf = (T < NKT - 1);
    int ktu = (T + 1) * 64;
    bf16x8 bfr[4][2];
#pragma unroll
    for (int ni = 0; ni < 4; ++ni) {
      bfr[ni][0] = *(const bf16x8*)(&sm[bro + ni * 1024 + gx0 * 8]);
      bfr[ni][1] = *(const bf16x8*)(&sm[bro + ni * 1024 + (gx0 ^ 4) * 8]);
    }
    LGKM0();
    PHASE_BAR();
    if (pf) { STAGE_B2(ktu); STAGE_A2(nxtA, ktu); }
    __builtin_amdgcn_s_setprio(1);
#pragma unroll
    for (int kk = 0; kk < 2; ++kk) {
      int gx = gx0 ^ (kk * 4);
      bf16x8 afr[4];
#pragma unroll
      for (int mi = 0; mi < 4; ++mi)
        afr[mi] = *(const bf16x8*)(&sm[curA + aro + mi * 1024 + gx * 8]);
#pragma unroll
      for (int mi = 0; mi < 4; ++mi)
#pragma unroll
        for (int ni = 0; ni < 4; ++ni)
          acc[mi][ni] = __builtin_amdgcn_mfma_f32_16x16x32_bf16(afr[mi], bfr[ni][kk], acc[mi][ni], 0, 0, 0);
    }
    __builtin_amdgcn_s_setprio(0);
    if (pf) {
      asm volatile("s_waitcnt vmcnt(0)" ::: "memory");
      PHASE_BAR();
    }
    curA = nxtA;
  }

#pragma unroll
  for (int mi = 0; mi < 4; ++mi) {
#pragma unroll
    for (int ni = 0; ni < 4; ++ni) {
      int col = bcol0 + wc * 64 + ni * 16 + lr;
      float bb = bout[col];
#pragma unroll
      for (int i = 0; i < 4; ++i) {
        size_t row = arow0 + wr * 64 + mi * 16 + g4 * 4 + i;
        F[row * 768 + col] = f2bf(tanhf(acc[mi][ni][i] + bb));
      }
    }
  }
#undef STAGE_A2
#undef STAGE_B2
}

// ---------------------------------------------------------------------------
#define GC 4
__global__ __launch_bounds__(256) void k_cos(
    const u16* __restrict__ F,    // [4096,768] bf16 (tanh applied)
    float* __restrict__ out)      // [B_]
{
  __shared__ float red[3][4];
  int t = threadIdx.x, b0 = blockIdx.x * GC;
  int lane = t & 63, wid = t >> 6;
  for (int g = 0; g < GC; ++g) {
    int b = b0 + g;
    float st = 0, si = 0, sd = 0;
#pragma unroll
    for (int j = 0; j < 3; ++j) {
      int c = t + j * 256;
      float rt = bf2f(F[(size_t)b * 768 + c]);
      float ri = bf2f(F[(size_t)(2048 + b) * 768 + c]);
      st += rt * rt; si += ri * ri; sd += rt * ri;
    }
#pragma unroll
    for (int off = 32; off >= 1; off >>= 1) {
      st += __shfl_down(st, off);
      si += __shfl_down(si, off);
      sd += __shfl_down(sd, off);
    }
    __syncthreads();
    if (lane == 0) { red[0][wid] = st; red[1][wid] = si; red[2][wid] = sd; }
    __syncthreads();
    if (t == 0) {
      float S1 = red[0][0] + red[0][1] + red[0][2] + red[0][3];
      float S2 = red[1][0] + red[1][1] + red[1][2] + red[1][3];
      float S3 = red[2][0] + red[2][1] + red[2][2] + red[2][3];
      out[b] = S3 / (fmaxf(sqrtf(S1), 1e-8f) * fmaxf(sqrtf(S2), 1e-8f));
    }
  }
}

// ---------------------------------------------------------------------------
extern "C" void kernel_launch(void* const* d_in, const int* in_sizes, int n_in,
                              void* d_out, int out_size, void* d_ws, size_t ws_size,
                              hipStream_t stream) {
  const float* features = (const float*)d_in[0];
  // d_in[1] = attention_mask (unused by forward)
  const float* w_qkv = (const float*)d_in[2];
  const float* b_qkv = (const float*)d_in[3];
  const float* w_out = (const float*)d_in[4];
  const float* b_out = (const float*)d_in[5];
  float* out = (float*)d_out;

  char* ws = (char*)d_ws;
  size_t off = 0;
  auto alloc = [&](size_t bytes) {
    void* p = ws + off;
    off += (bytes + 255) & ~(size_t)255;
    return p;
  };
  u8*  QK   = (u8*)alloc((size_t)M_ * TD2);          // 218 MB (fp8)
  u16* Wbf  = (u16*)alloc((size_t)2304 * D_ * 2);    // 3.5 MB
  u16* Wobf = (u16*)alloc((size_t)D_ * D_ * 2);      // 1.2 MB
  u16* Yv   = (u16*)alloc((size_t)4096 * 3072 * 2);  // 25 MB
  float* AT = (float*)alloc((size_t)B_ * 4 * SP * 4); // 2.4 MB
  float* AI = (float*)alloc((size_t)B_ * 4 * SP * 4); // 2.4 MB
  float* sat = (float*)alloc((size_t)4096 * 4 * 4);  // 64 KB
  u16* G    = (u16*)alloc((size_t)4096 * D_ * 2);    // 6.3 MB
  u16* F    = (u16*)alloc((size_t)4096 * D_ * 2);    // 6.3 MB
  (void)ws_size;

  hipLaunchKernelGGL(k_cvt_bf16, dim3((2304 * D_ / 8 + 255) / 256), dim3(256), 0, stream,
                     w_qkv, Wbf, 2304 * D_ / 8);
  hipLaunchKernelGGL(k_cvt_bf16, dim3((D_ * D_ / 8 + 255) / 256), dim3(256), 0, stream,
                     w_out, Wobf, D_ * D_ / 8);

  hipLaunchKernelGGL(k_gemm_qkv, dim3(6 * 1136), dim3(512), 0, stream,
                     features, Wbf, b_qkv, QK);
  hipLaunchKernelGGL(k_attn_qk, dim3(B_ * H_), dim3(256), 0, stream, QK, AT, AI, sat);
  hipLaunchKernelGGL(k_accy, dim3(B_), dim3(192), 0, stream, features, AT, AI, Yv);
  hipLaunchKernelGGL(k_gemm_v, dim3(32 * 12), dim3(256), 0, stream,
                     Yv, Wbf, b_qkv, sat, G);
  hipLaunchKernelGGL(k_gemm_head, dim3(32 * 3), dim3(512), 0, stream,
                     G, Wobf, b_out, F);
  hipLaunchKernelGGL(k_cos, dim3(B_ / GC), dim3(256), 0, stream, F, out);
}

// Round 21
// 635.969 us; speedup vs baseline: 1.3238x; 1.1179x over previous
//
#include <hip/hip_runtime.h>
#include <hip/hip_bf16.h>

#define B_ 2048
#define S_ 71
#define SP 72               // padded stride for at/ai
#define D_ 768
#define H_ 4
#define DH_ 192
#define TD2 1536            // q,k only
#define M_ (B_ * S_)        // 145408 = 1136*128
#define TEXT_ 35
#define NKT 12              // 768 / 64 K-tiles
#define NCH 852             // 71*12 16B chunks per (b,h) tensor

typedef unsigned short u16;
typedef unsigned char u8;
typedef unsigned int u32;
typedef __attribute__((ext_vector_type(2))) float f32x2;
typedef __attribute__((ext_vector_type(4))) float f32x4;
typedef __attribute__((ext_vector_type(8))) short bf16x8;

__device__ __forceinline__ u16 f2bf(float f) {
  u32 u = __float_as_uint(f);
  u32 r = (u + 0x7FFFu + ((u >> 16) & 1u)) >> 16;  // RNE
  return (u16)r;
}
__device__ __forceinline__ float bf2f(u16 x) {
  return __uint_as_float(((u32)x) << 16);
}
__device__ __forceinline__ u32 pk2bf(float lo, float hi) {
  __hip_bfloat162 h = __float22bfloat162_rn(float2{lo, hi});
  return *reinterpret_cast<u32*>(&h);
}

// ---- fp8 e4m3 codec: HW single-instruction path (gfx940+), guarded -------
#if __has_builtin(__builtin_amdgcn_cvt_pk_fp8_f32) && __has_builtin(__builtin_amdgcn_cvt_pk_f32_fp8)
__device__ __forceinline__ u32 enc4fp8(float a, float b, float c, float d) {
  int w = 0;
  w = __builtin_amdgcn_cvt_pk_fp8_f32(a, b, w, false);
  w = __builtin_amdgcn_cvt_pk_fp8_f32(c, d, w, true);
  return (u32)w;
}
__device__ __forceinline__ void dec4f(u32 v, float* f) {
  f32x2 a = __builtin_amdgcn_cvt_pk_f32_fp8((int)v, false);
  f32x2 b = __builtin_amdgcn_cvt_pk_f32_fp8((int)v, true);
  f[0] = a.x; f[1] = a.y; f[2] = b.x; f[3] = b.y;
}
#else
// branchless fallback (positive inputs)
__device__ __forceinline__ u8 f2fp8_1(float f) {
  f = fminf(f, 448.0f);
  u32 u = __float_as_uint(f);
  int e = (int)((u >> 23) & 0xFF) - 127;
  u32 m = u & 0x7FFFFF;
  u32 keep = m >> 20, rest = m & 0xFFFFF;
  u32 rb = (rest > 0x80000u) || (rest == 0x80000u && (keep & 1));
  u32 nrm = (((u32)(e + 7)) << 3) + keep + rb;
  u32 sub = (u32)__float2int_rn(f * 512.0f);
  u32 r = (e >= -6) ? nrm : ((e < -10) ? 0u : sub);
  return (u8)r;
}
__device__ __forceinline__ u32 enc4fp8(float a, float b, float c, float d) {
  return (u32)f2fp8_1(a) | ((u32)f2fp8_1(b) << 8) | ((u32)f2fp8_1(c) << 16) | ((u32)f2fp8_1(d) << 24);
}
__device__ __forceinline__ float fp82f(u32 v) {
  u32 e = (v >> 3) & 0xF, m = v & 7;
  float nrm = __uint_as_float(((e + 120) << 23) | (m << 20));
  return e ? nrm : (float)m * 0.001953125f;
}
__device__ __forceinline__ void dec4f(u32 v, float* f) {
  f[0] = fp82f(v & 0xFF); f[1] = fp82f((v >> 8) & 0xFF);
  f[2] = fp82f((v >> 16) & 0xFF); f[3] = fp82f(v >> 24);
}
#endif

typedef __attribute__((address_space(1))) const unsigned int GASU;
typedef __attribute__((address_space(3))) unsigned int LASU;
__device__ __forceinline__ void gload16(const void* g, void* l) {
  __builtin_amdgcn_global_load_lds((GASU*)g, (LASU*)l, 16, 0, 0);
}

#define PHASE_BAR() do { __builtin_amdgcn_s_barrier(); asm volatile("" ::: "memory"); } while (0)
#define LGKM0() do { asm volatile("s_waitcnt lgkmcnt(0)" ::: "memory"); __builtin_amdgcn_sched_barrier(0); } while (0)

// ---------------------------------------------------------------------------
__global__ __launch_bounds__(256) void k_cvt_bf16(const float* __restrict__ in,
                                                  u16* __restrict__ out, int n8) {
  int idx = blockIdx.x * 256 + threadIdx.x;
  if (idx >= n8) return;
  const float4* p = (const float4*)(in + (size_t)idx * 8);
  float4 a = p[0], b = p[1];
  uint4 o;
  o.x = pk2bf(a.x, a.y);
  o.y = pk2bf(a.z, a.w);
  o.z = pk2bf(b.x, b.y);
  o.w = pk2bf(b.z, b.w);
  *(uint4*)(out + (size_t)idx * 8) = o;
}

// ---------------------------------------------------------------------------
// Main GEMM — q,k only: C[M,1536] = phi(A(fp32)*Wqk^T + bias), fp8 out via
// HW codec. Proven geometry (r17/r20): 128x256 tile, BK=64, 8 waves, A
// reg-staged dbuf + B gload_lds, 64KB LDS, launch_bounds(512,4).
__global__ __launch_bounds__(512, 4) void k_gemm_qkv(
    const float* __restrict__ Afp,  // [M_,768] fp32 (features)
    const u16* __restrict__ Bw,     // [2304,768] bf16 (rows 0..1535 used)
    const float* __restrict__ bias, // [2304]
    u8* __restrict__ C)             // [M_,1536] fp8, phi everywhere
{
  __shared__ u16 sm[32768];   // 64 KiB
  int t = threadIdx.x;
  int lane = t & 63, wid = t >> 6;
  int wr = wid >> 2, wc = wid & 3;
  int lr = lane & 15;
  int g4 = lane >> 4;

  // XCD-bijective swizzle: nwg = 6816 = 8*852
  int swz = (blockIdx.x & 7) * 852 + (blockIdx.x >> 3);
  int bm = swz / 6, bn = swz % 6;
  const size_t arow0 = (size_t)bm * 128;
  const int bcol0 = bn * 256;

  const float* srcAf[2];
  int dA[2];
#pragma unroll
  for (int j = 0; j < 2; ++j) {
    int c = j * 512 + t;
    srcAf[j] = Afp + (arow0 + (c >> 3)) * 768 + ((c & 7) ^ ((c >> 3) & 7)) * 8;
    dA[j] = c * 8;
  }
  const u16* srcB[4];
  int dB[4];
#pragma unroll
  for (int j = 0; j < 4; ++j) {
    int c = j * 512 + t;
    srcB[j] = Bw + (size_t)(bcol0 + (c >> 3)) * 768 + ((c & 7) ^ ((c >> 3) & 7)) * 8;
    dB[j] = 16384 + c * 8;
  }

#define STAGE_B(ktu) do { \
  gload16(srcB[0] + (ktu), &sm[dB[0]]); \
  gload16(srcB[1] + (ktu), &sm[dB[1]]); \
  gload16(srcB[2] + (ktu), &sm[dB[2]]); \
  gload16(srcB[3] + (ktu), &sm[dB[3]]); \
} while (0)
#define LOADA(ktu) do { \
  fa0 = *(const float4*)(srcAf[0] + (ktu)); \
  fa1 = *(const float4*)(srcAf[0] + (ktu) + 4); \
  fa2 = *(const float4*)(srcAf[1] + (ktu)); \
  fa3 = *(const float4*)(srcAf[1] + (ktu) + 4); \
} while (0)
#define WRITEA(abuf) do { \
  uint4 o0; \
  o0.x = pk2bf(fa0.x, fa0.y); o0.y = pk2bf(fa0.z, fa0.w); \
  o0.z = pk2bf(fa1.x, fa1.y); o0.w = pk2bf(fa1.z, fa1.w); \
  *(uint4*)(&sm[(abuf) + dA[0]]) = o0; \
  uint4 o1; \
  o1.x = pk2bf(fa2.x, fa2.y); o1.y = pk2bf(fa2.z, fa2.w); \
  o1.z = pk2bf(fa3.x, fa3.y); o1.w = pk2bf(fa3.z, fa3.w); \
  *(uint4*)(&sm[(abuf) + dA[1]]) = o1; \
} while (0)

  int gx0 = g4 ^ (lr & 7);
  int aro = (wr * 64 + lr) * 64;
  int bro = 16384 + (wc * 64 + lr) * 64;

  f32x4 acc[4][4] = {};
  float4 fa0, fa1, fa2, fa3;

  LOADA(0);
  STAGE_B(0);
  asm volatile("s_waitcnt vmcnt(0)" ::: "memory");
  WRITEA(0);
  asm volatile("s_waitcnt lgkmcnt(0)" ::: "memory");
  PHASE_BAR();

  int curA = 0;
  for (int T = 0; T < NKT; ++T) {
    int nxtA = 8192 - curA;
    bool pf = (T < NKT - 1);
    int ktu = (T + 1) * 64;
    bf16x8 b0[4], a0[4];
#pragma unroll
    for (int ni = 0; ni < 4; ++ni) b0[ni] = *(const bf16x8*)(&sm[bro + ni * 1024 + gx0 * 8]);
#pragma unroll
    for (int mi = 0; mi < 4; ++mi) a0[mi] = *(const bf16x8*)(&sm[curA + aro + mi * 1024 + gx0 * 8]);
    __builtin_amdgcn_s_setprio(1);
#pragma unroll
    for (int mi = 0; mi < 4; ++mi)
#pragma unroll
      for (int ni = 0; ni < 4; ++ni)
        acc[mi][ni] = __builtin_amdgcn_mfma_f32_16x16x32_bf16(a0[mi], b0[ni], acc[mi][ni], 0, 0, 0);
    __builtin_amdgcn_s_setprio(0);
    int gx1 = gx0 ^ 4;
    bf16x8 b1[4];
#pragma unroll
    for (int ni = 0; ni < 4; ++ni) b1[ni] = *(const bf16x8*)(&sm[bro + ni * 1024 + gx1 * 8]);
    LGKM0();
    PHASE_BAR();                       // every wave's B reads done -> B free
    if (pf) { STAGE_B(ktu); LOADA(ktu); }
    bf16x8 a1[4];
#pragma unroll
    for (int mi = 0; mi < 4; ++mi) a1[mi] = *(const bf16x8*)(&sm[curA + aro + mi * 1024 + gx1 * 8]);
    __builtin_amdgcn_s_setprio(1);
#pragma unroll
    for (int mi = 0; mi < 4; ++mi)
#pragma unroll
      for (int ni = 0; ni < 4; ++ni)
        acc[mi][ni] = __builtin_amdgcn_mfma_f32_16x16x32_bf16(a1[mi], b1[ni], acc[mi][ni], 0, 0, 0);
    __builtin_amdgcn_s_setprio(0);
    if (pf) {
      asm volatile("s_waitcnt vmcnt(0)" ::: "memory");
      WRITEA(nxtA);
      asm volatile("s_waitcnt lgkmcnt(0)" ::: "memory");
      PHASE_BAR();
    }
    curA = nxtA;
  }

  // epilogue: bias + phi, fp8 out (HW packed encode, branchless)
#pragma unroll
  for (int mi = 0; mi < 4; ++mi) {
#pragma unroll
    for (int ni = 0; ni < 4; ++ni) {
      int col = bcol0 + wc * 64 + ni * 16 + lr;
      float bb = bias[col];
      float v[4];
#pragma unroll
      for (int i = 0; i < 4; ++i) {
        float x = acc[mi][ni][i] + bb;
        v[i] = (x > 0.0f) ? (x + 1.0f) : __expf(x);
      }
      u32 w = enc4fp8(v[0], v[1], v[2], v[3]);
      size_t r0 = arow0 + wr * 64 + mi * 16 + g4 * 4;
      C[(r0 + 0) * TD2 + col] = (u8)w;
      C[(r0 + 1) * TD2 + col] = (u8)(w >> 8);
      C[(r0 + 2) * TD2 + col] = (u8)(w >> 16);
      C[(r0 + 3) * TD2 + col] = (u8)(w >> 24);
    }
  }
#undef STAGE_B
#undef LOADA
#undef WRITEA
}

// ---------------------------------------------------------------------------
// Attention qk-phases v3: one block per (b,h). q,k held RAW fp8 in LDS
// (staged via gload_lds, zero staging VALU; unpadded [71][192B]); HW decode
// at point of use. LDS ~37 KB -> 4 blocks/CU (was 2). Phase math identical
// (fp8->f32 decode == fp8->bf16->f32 exactly; fp8 fits bf16 losslessly).
__global__ __launch_bounds__(256) void k_attn_qk(
    const u8* __restrict__ qk,    // [M_,1536] fp8 (phi applied)
    float* __restrict__ AT,       // [B_,4,SP]
    float* __restrict__ AI,       // [B_,4,SP]
    float* __restrict__ sat)      // [4096,4]
{
  __shared__ u32 q8[S_ * 48];   // 13632 B raw fp8
  __shared__ u32 k8[S_ * 48];   // 13632 B
  __shared__ float z[DH_], qt[DH_], qi[DH_];
  __shared__ float zqp[4][DH_];     // zp (z phase) then qp (qt phase)
  __shared__ float qip[4][DH_];
  __shared__ float wt[S_], wi[S_];
  __shared__ float at_l[S_ + 1], ai_l[S_ + 1];
  int t = threadIdx.x;
  int b = blockIdx.x >> 2, h = blockIdx.x & 3;
  size_t base = (size_t)b * S_ * TD2;
  int qoff = h * DH_, koff = 768 + h * DH_;
  int grp = t >> 4, gl = t & 15;
  int w = t >> 6, ln = t & 63;

  // ---- stage raw fp8 via gload_lds: chunk c -> row s=c/12, col (c%12)*16.
  // LDS dest = wave-uniform base + lane*16 (linear over the 13632B block).
#pragma unroll
  for (int j = 0; j < 4; ++j) {
    int c = j * 256 + t;
    int s = c / 12, cc = (c % 12) * 16;
    const u8* gq = qk + base + (size_t)s * TD2 + qoff + cc;
    const u8* gk = qk + base + (size_t)s * TD2 + koff + cc;
    char* dq = (char*)q8 + (size_t)(j * 256 + w * 64) * 16;
    char* dk = (char*)k8 + (size_t)(j * 256 + w * 64) * 16;
    if (c < NCH) {
      gload16(gq, dq);
      gload16(gk, dk);
    }
  }
  asm volatile("s_waitcnt vmcnt(0)" ::: "memory");
  __syncthreads();
  // ---- z[d] = sum_s k[s,d]: 48 lanes/wave, 4 d's each, s-chunk per wave
  if (ln < 48) {
    int s0 = w * 18, s1 = (w == 3) ? S_ : (s0 + 18);
    float p[4] = {};
    for (int s = s0; s < s1; ++s) {
      float f[4];
      dec4f(k8[s * 48 + ln], f);
      p[0] += f[0]; p[1] += f[1]; p[2] += f[2]; p[3] += f[3];
    }
#pragma unroll
    for (int j = 0; j < 4; ++j) zqp[w][ln * 4 + j] = p[j];
  }
  __syncthreads();
  if (t < DH_) z[t] = (zqp[0][t] + zqp[1][t]) + (zqp[2][t] + zqp[3][t]);
  __syncthreads();
  // ---- den[s] = q[s,:].z — 16-lane groups, 12 d's (3 u32) per lane
  for (int s = grp; s < S_; s += 16) {
    float f[12];
    int g0 = s * 48 + gl * 3;
    dec4f(q8[g0], f); dec4f(q8[g0 + 1], f + 4); dec4f(q8[g0 + 2], f + 8);
    float a = 0;
    int d0 = gl * 12;
#pragma unroll
    for (int i = 0; i < 12; ++i) a += f[i] * z[d0 + i];
#pragma unroll
    for (int o = 8; o >= 1; o >>= 1) a += __shfl_xor(a, o);
    if (gl == 0) {
      float den = a + 1e-6f;
      wt[s] = (s < TEXT_) ? 1.0f / (35.0f * den) : 0.0f;
      wi[s] = (s >= TEXT_) ? 1.0f / (36.0f * den) : 0.0f;
    }
  }
  __syncthreads();
  // ---- qt[d], qi[d] = sum_s q[s,d]*w[s]: 48 lanes/wave, 4 d's each
  if (ln < 48) {
    int s0 = w * 18, s1 = (w == 3) ? S_ : (s0 + 18);
    float pt[4] = {}, pi[4] = {};
    for (int s = s0; s < s1; ++s) {
      float wts = wt[s], wis = wi[s];
      float f[4];
      dec4f(q8[s * 48 + ln], f);
#pragma unroll
      for (int j = 0; j < 4; ++j) { pt[j] += f[j] * wts; pi[j] += f[j] * wis; }
    }
#pragma unroll
    for (int j = 0; j < 4; ++j) { zqp[w][ln * 4 + j] = pt[j]; qip[w][ln * 4 + j] = pi[j]; }
  }
  __syncthreads();
  if (t < DH_) {
    qt[t] = (zqp[0][t] + zqp[1][t]) + (zqp[2][t] + zqp[3][t]);
    qi[t] = (qip[0][t] + qip[1][t]) + (qip[2][t] + qip[3][t]);
  }
  __syncthreads();
  // ---- at[s], ai[s] = k[s,:].qt/.qi — 16-lane groups
  size_t arow = ((size_t)b * 4 + h) * SP;
  for (int s = grp; s < S_; s += 16) {
    float f[12];
    int g0 = s * 48 + gl * 3;
    dec4f(k8[g0], f); dec4f(k8[g0 + 1], f + 4); dec4f(k8[g0 + 2], f + 8);
    float aT = 0, aI = 0;
    int d0 = gl * 12;
#pragma unroll
    for (int i = 0; i < 12; ++i) { aT += f[i] * qt[d0 + i]; aI += f[i] * qi[d0 + i]; }
#pragma unroll
    for (int o = 8; o >= 1; o >>= 1) { aT += __shfl_xor(aT, o); aI += __shfl_xor(aI, o); }
    if (gl == 0) {
      at_l[s] = aT; ai_l[s] = aI;
      AT[arow + s] = aT; AI[arow + s] = aI;
    }
  }
  __syncthreads();
  if (t < 64) {
    float vT = at_l[t] + ((t < 7) ? at_l[t + 64] : 0.0f);
    float vI = ai_l[t] + ((t < 7) ? ai_l[t + 64] : 0.0f);
#pragma unroll
    for (int o = 32; o >= 1; o >>= 1) { vT += __shfl_xor(vT, o); vI += __shfl_xor(vI, o); }
    if (t == 0) {
      sat[(size_t)b * 4 + h] = vT;
      sat[(size_t)(2048 + b) * 4 + h] = vI;
    }
  }
}

// ---------------------------------------------------------------------------
// Y accumulation: block per b, 192 threads; streams x once (float4).
__global__ __launch_bounds__(192) void k_accy(
    const float* __restrict__ x,  // [B_,71,768] fp32
    const float* __restrict__ AT, // [B_,4,SP]
    const float* __restrict__ AI,
    u16* __restrict__ Y)          // [4096,3072] bf16
{
  __shared__ float at_s[4][S_], ai_s[4][S_];
  int t = threadIdx.x, b = blockIdx.x;
  for (int i = t; i < 4 * S_; i += 192) {
    int h = i / S_, s = i % S_;
    at_s[h][s] = AT[((size_t)b * 4 + h) * SP + s];
    ai_s[h][s] = AI[((size_t)b * 4 + h) * SP + s];
  }
  __syncthreads();
  float4 yt[4] = {}, yi[4] = {};
  const float4* xb = (const float4*)(x + (size_t)b * S_ * 768);
  for (int s = 0; s < S_; ++s) {
    float4 xv = xb[s * 192 + t];
#pragma unroll
    for (int h = 0; h < 4; ++h) {
      float a = at_s[h][s], ai_ = ai_s[h][s];
      yt[h].x += a * xv.x; yt[h].y += a * xv.y; yt[h].z += a * xv.z; yt[h].w += a * xv.w;
      yi[h].x += ai_ * xv.x; yi[h].y += ai_ * xv.y; yi[h].z += ai_ * xv.z; yi[h].w += ai_ * xv.w;
    }
  }
  size_t rt = (size_t)b * 3072, ri = (size_t)(2048 + b) * 3072;
#pragma unroll
  for (int h = 0; h < 4; ++h) {
    uint2 ot, oi;
    ot.x = pk2bf(yt[h].x, yt[h].y); ot.y = pk2bf(yt[h].z, yt[h].w);
    oi.x = pk2bf(yi[h].x, yi[h].y); oi.y = pk2bf(yi[h].z, yi[h].w);
    *(uint2*)(&Y[rt + h * 768 + t * 4]) = ot;
    *(uint2*)(&Y[ri + h * 768 + t * 4]) = oi;
  }
}

// ---------------------------------------------------------------------------
// Grouped v-GEMM: G[4096][768] = Y_h * Wv_h^T + sat*bv (per head h).
__global__ __launch_bounds__(256, 4) void k_gemm_v(
    const u16* __restrict__ Yb,    // [4096,3072] bf16
    const u16* __restrict__ Wbf,   // [2304,768] bf16 (rows 1536+ = Wv)
    const float* __restrict__ bqkv,
    const float* __restrict__ sat, // [4096,4]
    u16* __restrict__ G)           // [4096,768] bf16
{
  __shared__ u16 sm[24576];
  int t = threadIdx.x;
  int lane = t & 63, wid = t >> 6;
  int wr = wid >> 1, wc = wid & 1;
  int lr = lane & 15, g4 = lane >> 4;
  int bm = blockIdx.x / 12, nt = blockIdx.x % 12;
  int h = nt / 3, e0 = (nt % 3) * 64;
  const size_t arow0 = (size_t)bm * 128;

  const u16* srcA[4];
  int dA[4];
#pragma unroll
  for (int j = 0; j < 4; ++j) {
    int c = j * 256 + t;
    int row = c >> 3, kg = (c & 7) ^ (row & 7);
    srcA[j] = Yb + (arow0 + row) * 3072 + h * 768 + kg * 8;
    dA[j] = c * 8;
  }
  const u16* srcB[2];
  int dB[2];
#pragma unroll
  for (int j = 0; j < 2; ++j) {
    int c = j * 256 + t;
    int row = c >> 3, kg = (c & 7) ^ (row & 7);
    srcB[j] = Wbf + (size_t)(1536 + h * DH_ + e0 + row) * 768 + kg * 8;
    dB[j] = c * 8;
  }

#define VSTAGE(abuf, bbuf, ktu) do { \
  gload16(srcA[0] + (ktu), &sm[(abuf) + dA[0]]); \
  gload16(srcA[1] + (ktu), &sm[(abuf) + dA[1]]); \
  gload16(srcA[2] + (ktu), &sm[(abuf) + dA[2]]); \
  gload16(srcA[3] + (ktu), &sm[(abuf) + dA[3]]); \
  gload16(srcB[0] + (ktu), &sm[(bbuf) + dB[0]]); \
  gload16(srcB[1] + (ktu), &sm[(bbuf) + dB[1]]); \
} while (0)

  int gx0 = g4 ^ (lr & 7);
  int aro = (wr * 64 + lr) * 64;
  int bro = (wc * 32 + lr) * 64;

  f32x4 acc[4][2] = {};

  VSTAGE(0, 16384, 0);
  asm volatile("s_waitcnt vmcnt(0)" ::: "memory");
  PHASE_BAR();

  for (int T = 0; T < NKT; ++T) {
    int abuf = (T & 1) * 8192, bbuf = 16384 + (T & 1) * 4096;
    bool pf = (T < NKT - 1);
    if (pf) VSTAGE(8192 - abuf, 20480 - (T & 1) * 4096, (T + 1) * 64);
#pragma unroll
    for (int kk = 0; kk < 2; ++kk) {
      int gx = gx0 ^ (kk * 4);
      bf16x8 a[4], bfr[2];
#pragma unroll
      for (int mi = 0; mi < 4; ++mi) a[mi] = *(const bf16x8*)(&sm[abuf + aro + mi * 1024 + gx * 8]);
#pragma unroll
      for (int ni = 0; ni < 2; ++ni) bfr[ni] = *(const bf16x8*)(&sm[bbuf + bro + ni * 1024 + gx * 8]);
#pragma unroll
      for (int mi = 0; mi < 4; ++mi)
#pragma unroll
        for (int ni = 0; ni < 2; ++ni)
          acc[mi][ni] = __builtin_amdgcn_mfma_f32_16x16x32_bf16(a[mi], bfr[ni], acc[mi][ni], 0, 0, 0);
    }
    if (pf) {
      asm volatile("s_waitcnt vmcnt(0)" ::: "memory");
      PHASE_BAR();
    }
  }

#pragma unroll
  for (int mi = 0; mi < 4; ++mi) {
#pragma unroll
    for (int ni = 0; ni < 2; ++ni) {
      int e = e0 + wc * 32 + ni * 16 + lr;
      int gcol = h * DH_ + e;
      float bv = bqkv[1536 + gcol];
#pragma unroll
      for (int i = 0; i < 4; ++i) {
        size_t row = arow0 + wr * 64 + mi * 16 + g4 * 4 + i;
        G[row * 768 + gcol] = f2bf(acc[mi][ni][i] + sat[row * 4 + h] * bv);
      }
    }
  }
#undef VSTAGE
}

// ---------------------------------------------------------------------------
// Head GEMM: F = tanh(G * w_out^T + b_out)
__global__ __launch_bounds__(512, 4) void k_gemm_head(
    const u16* __restrict__ Gb,   // [4096,768] bf16
    const u16* __restrict__ Wo,   // [768,768] bf16 (n-major)
    const float* __restrict__ bout,
    u16* __restrict__ F)          // [4096,768] bf16
{
  __shared__ u16 sm[32768];
  int t = threadIdx.x;
  int lane = t & 63, wid = t >> 6;
  int wr = wid >> 2, wc = wid & 3;
  int lr = lane & 15;
  int g4 = lane >> 4;

  int bm = blockIdx.x / 3, bn = blockIdx.x % 3;
  const size_t arow0 = (size_t)bm * 128;
  const int bcol0 = bn * 256;

  const u16* srcA[2];
  int dA[2];
#pragma unroll
  for (int j = 0; j < 2; ++j) {
    int c = j * 512 + t;
    srcA[j] = Gb + (arow0 + (c >> 3)) * 768 + ((c & 7) ^ ((c >> 3) & 7)) * 8;
    dA[j] = c * 8;
  }
  const u16* srcB[4];
  int dB[4];
#pragma unroll
  for (int j = 0; j < 4; ++j) {
    int c = j * 512 + t;
    srcB[j] = Wo + (size_t)(bcol0 + (c >> 3)) * 768 + ((c & 7) ^ ((c >> 3) & 7)) * 8;
    dB[j] = 16384 + c * 8;
  }

#define STAGE_A2(abuf, ktu) do { \
  gload16(srcA[0] + (ktu), &sm[(abuf) + dA[0]]); \
  gload16(srcA[1] + (ktu), &sm[(abuf) + dA[1]]); \
} while (0)
#define STAGE_B2(ktu) do { \
  gload16(srcB[0] + (ktu), &sm[dB[0]]); \
  gload16(srcB[1] + (ktu), &sm[dB[1]]); \
  gload16(srcB[2] + (ktu), &sm[dB[2]]); \
  gload16(srcB[3] + (ktu), &sm[dB[3]]); \
} while (0)

  int gx0 = g4 ^ (lr & 7);
  int aro = (wr * 64 + lr) * 64;
  int bro = 16384 + (wc * 64 + lr) * 64;

  f32x4 acc[4][4] = {};

  STAGE_A2(0, 0); STAGE_B2(0);
  asm volatile("s_waitcnt vmcnt(0)" ::: "memory");
  PHASE_BAR();

  int curA = 0;
  for (int T = 0; T < NKT; ++T) {
    int nxtA = 8192 - curA;
    bool pf = (T < NKT - 1);
    int ktu = (T + 1) * 64;
    bf16x8 bfr[4][2];
#pragma unroll
    for (int ni = 0; ni < 4; ++ni) {
      bfr[ni][0] = *(const bf16x8*)(&sm[bro + ni * 1024 + gx0 * 8]);
      bfr[ni][1] = *(const bf16x8*)(&sm[bro + ni * 1024 + (gx0 ^ 4) * 8]);
    }
    LGKM0();
    PHASE_BAR();
    if (pf) { STAGE_B2(ktu); STAGE_A2(nxtA, ktu); }
    __builtin_amdgcn_s_setprio(1);
#pragma unroll
    for (int kk = 0; kk < 2; ++kk) {
      int gx = gx0 ^ (kk * 4);
      bf16x8 afr[4];
#pragma unroll
      for (int mi = 0; mi < 4; ++mi)
        afr[mi] = *(const bf16x8*)(&sm[curA + aro + mi * 1024 + gx * 8]);
#pragma unroll
      for (int mi = 0; mi < 4; ++mi)
#pragma unroll
        for (int ni = 0; ni < 4; ++ni)
          acc[mi][ni] = __builtin_amdgcn_mfma_f32_16x16x32_bf16(afr[mi], bfr[ni][kk], acc[mi][ni], 0, 0, 0);
    }
    __builtin_amdgcn_s_setprio(0);
    if (pf) {
      asm volatile("s_waitcnt vmcnt(0)" ::: "memory");
      PHASE_BAR();
    }
    curA = nxtA;
  }

#pragma unroll
  for (int mi = 0; mi < 4; ++mi) {
#pragma unroll
    for (int ni = 0; ni < 4; ++ni) {
      int col = bcol0 + wc * 64 + ni * 16 + lr;
      float bb = bout[col];
#pragma unroll
      for (int i = 0; i < 4; ++i) {
        size_t row = arow0 + wr * 64 + mi * 16 + g4 * 4 + i;
        F[row * 768 + col] = f2bf(tanhf(acc[mi][ni][i] + bb));
      }
    }
  }
#undef STAGE_A2
#undef STAGE_B2
}

// ---------------------------------------------------------------------------
#define GC 4
__global__ __launch_bounds__(256) void k_cos(
    const u16* __restrict__ F,    // [4096,768] bf16 (tanh applied)
    float* __restrict__ out)      // [B_]
{
  __shared__ float red[3][4];
  int t = threadIdx.x, b0 = blockIdx.x * GC;
  int lane = t & 63, wid = t >> 6;
  for (int g = 0; g < GC; ++g) {
    int b = b0 + g;
    float st = 0, si = 0, sd = 0;
#pragma unroll
    for (int j = 0; j < 3; ++j) {
      int c = t + j * 256;
      float rt = bf2f(F[(size_t)b * 768 + c]);
      float ri = bf2f(F[(size_t)(2048 + b) * 768 + c]);
      st += rt * rt; si += ri * ri; sd += rt * ri;
    }
#pragma unroll
    for (int off = 32; off >= 1; off >>= 1) {
      st += __shfl_down(st, off);
      si += __shfl_down(si, off);
      sd += __shfl_down(sd, off);
    }
    __syncthreads();
    if (lane == 0) { red[0][wid] = st; red[1][wid] = si; red[2][wid] = sd; }
    __syncthreads();
    if (t == 0) {
      float S1 = red[0][0] + red[0][1] + red[0][2] + red[0][3];
      float S2 = red[1][0] + red[1][1] + red[1][2] + red[1][3];
      float S3 = red[2][0] + red[2][1] + red[2][2] + red[2][3];
      out[b] = S3 / (fmaxf(sqrtf(S1), 1e-8f) * fmaxf(sqrtf(S2), 1e-8f));
    }
  }
}

// ---------------------------------------------------------------------------
extern "C" void kernel_launch(void* const* d_in, const int* in_sizes, int n_in,
                              void* d_out, int out_size, void* d_ws, size_t ws_size,
                              hipStream_t stream) {
  const float* features = (const float*)d_in[0];
  // d_in[1] = attention_mask (unused by forward)
  const float* w_qkv = (const float*)d_in[2];
  const float* b_qkv = (const float*)d_in[3];
  const float* w_out = (const float*)d_in[4];
  const float* b_out = (const float*)d_in[5];
  float* out = (float*)d_out;

  char* ws = (char*)d_ws;
  size_t off = 0;
  auto alloc = [&](size_t bytes) {
    void* p = ws + off;
    off += (bytes + 255) & ~(size_t)255;
    return p;
  };
  u8*  QK   = (u8*)alloc((size_t)M_ * TD2);          // 218 MB (fp8)
  u16* Wbf  = (u16*)alloc((size_t)2304 * D_ * 2);    // 3.5 MB
  u16* Wobf = (u16*)alloc((size_t)D_ * D_ * 2);      // 1.2 MB
  u16* Yv   = (u16*)alloc((size_t)4096 * 3072 * 2);  // 25 MB
  float* AT = (float*)alloc((size_t)B_ * 4 * SP * 4); // 2.4 MB
  float* AI = (float*)alloc((size_t)B_ * 4 * SP * 4); // 2.4 MB
  float* sat = (float*)alloc((size_t)4096 * 4 * 4);  // 64 KB
  u16* G    = (u16*)alloc((size_t)4096 * D_ * 2);    // 6.3 MB
  u16* F    = (u16*)alloc((size_t)4096 * D_ * 2);    // 6.3 MB
  (void)ws_size;

  hipLaunchKernelGGL(k_cvt_bf16, dim3((2304 * D_ / 8 + 255) / 256), dim3(256), 0, stream,
                     w_qkv, Wbf, 2304 * D_ / 8);
  hipLaunchKernelGGL(k_cvt_bf16, dim3((D_ * D_ / 8 + 255) / 256), dim3(256), 0, stream,
                     w_out, Wobf, D_ * D_ / 8);

  hipLaunchKernelGGL(k_gemm_qkv, dim3(6 * 1136), dim3(512), 0, stream,
                     features, Wbf, b_qkv, QK);
  hipLaunchKernelGGL(k_attn_qk, dim3(B_ * H_), dim3(256), 0, stream, QK, AT, AI, sat);
  hipLaunchKernelGGL(k_accy, dim3(B_), dim3(192), 0, stream, features, AT, AI, Yv);
  hipLaunchKernelGGL(k_gemm_v, dim3(32 * 12), dim3(256), 0, stream,
                     Yv, Wbf, b_qkv, sat, G);
  hipLaunchKernelGGL(k_gemm_head, dim3(32 * 3), dim3(512), 0, stream,
                     G, Wobf, b_out, F);
  hipLaunchKernelGGL(k_cos, dim3(B_ / GC), dim3(256), 0, stream, F, out);
}

// Round 22
// 612.100 us; speedup vs baseline: 1.3754x; 1.0390x over previous
//
#include <hip/hip_runtime.h>
#include <hip/hip_bf16.h>

#define B_ 2048
#define S_ 71
#define SP 72               // padded stride for at/ai
#define D_ 768
#define H_ 4
#define DH_ 192
#define TD2 1536            // q,k only
#define M_ (B_ * S_)        // 145408 = 1136*128
#define TEXT_ 35
#define NKT 12              // 768 / 64 K-tiles (bf16 kernels)
#define NK8 6               // 768 / 128 K-tiles (fp8 main GEMM)
#define NCH 852             // 71*12 16B chunks per (b,h) tensor

typedef unsigned short u16;
typedef unsigned char u8;
typedef unsigned int u32;
typedef long long i64;
typedef __attribute__((ext_vector_type(2))) float f32x2;
typedef __attribute__((ext_vector_type(4))) float f32x4;
typedef __attribute__((ext_vector_type(8))) short bf16x8;

__device__ __forceinline__ u16 f2bf(float f) {
  u32 u = __float_as_uint(f);
  u32 r = (u + 0x7FFFu + ((u >> 16) & 1u)) >> 16;  // RNE
  return (u16)r;
}
__device__ __forceinline__ float bf2f(u16 x) {
  return __uint_as_float(((u32)x) << 16);
}
__device__ __forceinline__ u32 pk2bf(float lo, float hi) {
  __hip_bfloat162 h = __float22bfloat162_rn(float2{lo, hi});
  return *reinterpret_cast<u32*>(&h);
}

// ---- fp8 e4m3 codec: HW single-instruction path (gfx940+), guarded -------
#if __has_builtin(__builtin_amdgcn_cvt_pk_fp8_f32) && __has_builtin(__builtin_amdgcn_cvt_pk_f32_fp8)
__device__ __forceinline__ u32 enc4fp8(float a, float b, float c, float d) {
  int w = 0;
  w = __builtin_amdgcn_cvt_pk_fp8_f32(a, b, w, false);
  w = __builtin_amdgcn_cvt_pk_fp8_f32(c, d, w, true);
  return (u32)w;
}
__device__ __forceinline__ void dec4f(u32 v, float* f) {
  f32x2 a = __builtin_amdgcn_cvt_pk_f32_fp8((int)v, false);
  f32x2 b = __builtin_amdgcn_cvt_pk_f32_fp8((int)v, true);
  f[0] = a.x; f[1] = a.y; f[2] = b.x; f[3] = b.y;
}
#else
__device__ __forceinline__ u8 f2fp8_1(float f) {
  float sgn = (f < 0.f) ? -1.f : 1.f;
  f = fabsf(f);
  f = fminf(f, 448.0f);
  u32 u = __float_as_uint(f);
  int e = (int)((u >> 23) & 0xFF) - 127;
  u32 m = u & 0x7FFFFF;
  u32 keep = m >> 20, rest = m & 0xFFFFF;
  u32 rb = (rest > 0x80000u) || (rest == 0x80000u && (keep & 1));
  u32 nrm = (((u32)(e + 7)) << 3) + keep + rb;
  u32 sub = (u32)__float2int_rn(f * 512.0f);
  u32 r = (e >= -6) ? nrm : ((e < -10) ? 0u : sub);
  return (u8)(r | (sgn < 0.f ? 0x80u : 0u));
}
__device__ __forceinline__ u32 enc4fp8(float a, float b, float c, float d) {
  return (u32)f2fp8_1(a) | ((u32)f2fp8_1(b) << 8) | ((u32)f2fp8_1(c) << 16) | ((u32)f2fp8_1(d) << 24);
}
__device__ __forceinline__ float fp82f1(u32 v) {
  u32 s = v >> 7, e = (v >> 3) & 0xF, m = v & 7;
  float nrm = __uint_as_float(((e + 120) << 23) | (m << 20));
  float r = e ? nrm : (float)m * 0.001953125f;
  return s ? -r : r;
}
__device__ __forceinline__ void dec4f(u32 v, float* f) {
  f[0] = fp82f1(v & 0xFF); f[1] = fp82f1((v >> 8) & 0xFF);
  f[2] = fp82f1((v >> 16) & 0xFF); f[3] = fp82f1(v >> 24);
}
#endif

typedef __attribute__((address_space(1))) const unsigned int GASU;
typedef __attribute__((address_space(3))) unsigned int LASU;
__device__ __forceinline__ void gload16(const void* g, void* l) {
  __builtin_amdgcn_global_load_lds((GASU*)g, (LASU*)l, 16, 0, 0);
}

#define PHASE_BAR() do { __builtin_amdgcn_s_barrier(); asm volatile("" ::: "memory"); } while (0)
#define LGKM0() do { asm volatile("s_waitcnt lgkmcnt(0)" ::: "memory"); __builtin_amdgcn_sched_barrier(0); } while (0)

// ---------------------------------------------------------------------------
__global__ __launch_bounds__(256) void k_cvt_bf16(const float* __restrict__ in,
                                                  u16* __restrict__ out, int n8) {
  int idx = blockIdx.x * 256 + threadIdx.x;
  if (idx >= n8) return;
  const float4* p = (const float4*)(in + (size_t)idx * 8);
  float4 a = p[0], b = p[1];
  uint4 o;
  o.x = pk2bf(a.x, a.y);
  o.y = pk2bf(a.z, a.w);
  o.z = pk2bf(b.x, b.y);
  o.w = pk2bf(b.z, b.w);
  *(uint4*)(out + (size_t)idx * 8) = o;
}

// w_qk (rows 0..1535 of w_qkv) -> fp8 with x64 scale (keeps 0.02-scale
// weights in e4m3 normal range; GEMM epilogue divides by 64).
__global__ __launch_bounds__(256) void k_cvt_w8(const float* __restrict__ in,
                                                u8* __restrict__ out, int n16) {
  int idx = blockIdx.x * 256 + threadIdx.x;
  if (idx >= n16) return;
  const float4* p = (const float4*)(in + (size_t)idx * 16);
  float4 a = p[0], b = p[1], c = p[2], d = p[3];
  uint4 o;
  o.x = enc4fp8(a.x * 64.f, a.y * 64.f, a.z * 64.f, a.w * 64.f);
  o.y = enc4fp8(b.x * 64.f, b.y * 64.f, b.z * 64.f, b.w * 64.f);
  o.z = enc4fp8(c.x * 64.f, c.y * 64.f, c.z * 64.f, c.w * 64.f);
  o.w = enc4fp8(d.x * 64.f, d.y * 64.f, d.z * 64.f, d.w * 64.f);
  *(uint4*)(out + (size_t)idx * 16) = o;
}

// ---------------------------------------------------------------------------
// Main GEMM — fp8 x fp8 MFMA (16x16x32_fp8_fp8, same rate as bf16 but half
// the operand traffic): C[M,1536] = phi(A*Wqk^T + bias), fp8 out.
// 128x256 tile, BK=128 (6 K-tiles -> HALF the barrier/drain count of the
// bf16 build), 8 waves, A fp32->fp8 reg-staged dbuf (2x16KB), B fp8
// gload_lds single (32KB) = 64KB LDS, 2 blocks/CU. 16B-chunk XOR swizzle
// (cc^(row&7)) gives <=2-way (free) banks on the b64 fragment reads.
// B is w*64 in fp8; epilogue multiplies by 1/64.
__global__ __launch_bounds__(512, 4) void k_gemm_qkv(
    const float* __restrict__ Afp,  // [M_,768] fp32 (features)
    const u8* __restrict__ Wf8,     // [1536,768] fp8 (w*64)
    const float* __restrict__ bias, // [2304]
    u8* __restrict__ C)             // [M_,1536] fp8, phi everywhere
{
  __shared__ u8 sm8[65536];   // A0 [0,16K) A1 [16K,32K) B [32K,64K)
  int t = threadIdx.x;
  int lane = t & 63, wid = t >> 6;
  int wr = wid >> 2, wc = wid & 3;
  int lr = lane & 15;
  int g4 = lane >> 4;

  // XCD-bijective swizzle: nwg = 6816 = 8*852
  int swz = (blockIdx.x & 7) * 852 + (blockIdx.x >> 3);
  int bm = swz / 6, bn = swz % 6;
  const size_t arow0 = (size_t)bm * 128;
  const int bcol0 = bn * 256;

  // A: 1024 16-elem chunks (16 fp32 -> 16B fp8), 2/thread, sequential.
  const float* srcAf[2];
  int dA[2];
#pragma unroll
  for (int j = 0; j < 2; ++j) {
    int c = j * 512 + t;
    int row = c >> 3, cc = c & 7;
    srcAf[j] = Afp + (arow0 + row) * 768 + ((cc ^ (row & 7)) * 16);
    dA[j] = c * 16;
  }
  // B: 2048 16B chunks, 4/thread via gload_lds (source pre-swizzled).
  const u8* srcB[4];
  int dB[4];
#pragma unroll
  for (int j = 0; j < 4; ++j) {
    int c = j * 512 + t;
    int row = c >> 3, cc = c & 7;
    srcB[j] = Wf8 + (size_t)(bcol0 + row) * 768 + ((cc ^ (row & 7)) * 16);
    dB[j] = 32768 + c * 16;
  }

#define STAGE_B(ktu) do { \
  gload16(srcB[0] + (ktu), &sm8[dB[0]]); \
  gload16(srcB[1] + (ktu), &sm8[dB[1]]); \
  gload16(srcB[2] + (ktu), &sm8[dB[2]]); \
  gload16(srcB[3] + (ktu), &sm8[dB[3]]); \
} while (0)
#define LOADA(j, ktu) do { \
  const float4* p_ = (const float4*)(srcAf[j] + (ktu)); \
  fa0 = p_[0]; fa1 = p_[1]; fa2 = p_[2]; fa3 = p_[3]; \
} while (0)
#define WRITEA(j, abuf) do { \
  uint4 o_; \
  o_.x = enc4fp8(fa0.x, fa0.y, fa0.z, fa0.w); \
  o_.y = enc4fp8(fa1.x, fa1.y, fa1.z, fa1.w); \
  o_.z = enc4fp8(fa2.x, fa2.y, fa2.z, fa2.w); \
  o_.w = enc4fp8(fa3.x, fa3.y, fa3.z, fa3.w); \
  *(uint4*)(&sm8[(abuf) + dA[j]]) = o_; \
} while (0)

  // fragment addressing: row = base+lr (bases mult of 16 => row&7 == lr&7).
  // granule g = kk*4+g4 (8 fp8); byte = row*128 + ((g>>1)^(lr&7))*16 + (g&1)*8
  int offk[4];
#pragma unroll
  for (int kk = 0; kk < 4; ++kk)
    offk[kk] = (((kk * 2 + (g4 >> 1)) ^ (lr & 7)) * 16) + (g4 & 1) * 8;
  int aro = (wr * 64 + lr) * 128;            // + mi*2048 + offk
  int bro = 32768 + (wc * 64 + lr) * 128;    // + ni*2048 + offk

  f32x4 acc[4][4] = {};
  float4 fa0, fa1, fa2, fa3;

  // prologue: A loads FIRST (oldest -> counted-vmcnt retires them first)
  LOADA(0, 0);
  STAGE_B(0);
  asm volatile("s_waitcnt vmcnt(16)" ::: "memory");   // A c0 landed
  WRITEA(0, 0);
  LOADA(1, 0);
  asm volatile("s_waitcnt vmcnt(0)" ::: "memory");    // c1 + B landed
  WRITEA(1, 0);
  asm volatile("s_waitcnt lgkmcnt(0)" ::: "memory");
  PHASE_BAR();

  int curA = 0;
  for (int T = 0; T < NK8; ++T) {
    int nxtA = 16384 - curA;
    bool pf = (T < NK8 - 1);
    int ktu = (T + 1) * 128;
    // q0..q2: per quarter read B+A frags, MFMA
    i64 b3[4];
#pragma unroll
    for (int kk = 0; kk < 3; ++kk) {
      i64 bfr[4], afr[4];
#pragma unroll
      for (int ni = 0; ni < 4; ++ni) bfr[ni] = *(const i64*)(&sm8[bro + ni * 2048 + offk[kk]]);
#pragma unroll
      for (int mi = 0; mi < 4; ++mi) afr[mi] = *(const i64*)(&sm8[curA + aro + mi * 2048 + offk[kk]]);
      __builtin_amdgcn_s_setprio(1);
#pragma unroll
      for (int mi = 0; mi < 4; ++mi)
#pragma unroll
        for (int ni = 0; ni < 4; ++ni)
          acc[mi][ni] = __builtin_amdgcn_mfma_f32_16x16x32_fp8_fp8((long)afr[mi], (long)bfr[ni], acc[mi][ni], 0, 0, 0);
      __builtin_amdgcn_s_setprio(0);
    }
    // pre-read B kk3 into regs, then barrier frees the B buffer
#pragma unroll
    for (int ni = 0; ni < 4; ++ni) b3[ni] = *(const i64*)(&sm8[bro + ni * 2048 + offk[3]]);
    LGKM0();
    PHASE_BAR();
    if (pf) { LOADA(0, ktu); STAGE_B(ktu); }
    // q3: A frags kk3 from cur (no writer), MFMA on pre-read B
    i64 a3[4];
#pragma unroll
    for (int mi = 0; mi < 4; ++mi) a3[mi] = *(const i64*)(&sm8[curA + aro + mi * 2048 + offk[3]]);
    if (pf) {
      asm volatile("s_waitcnt vmcnt(16)" ::: "memory");  // A c0 landed
      WRITEA(0, nxtA);
      LOADA(1, ktu);
    }
    __builtin_amdgcn_s_setprio(1);
#pragma unroll
    for (int mi = 0; mi < 4; ++mi)
#pragma unroll
      for (int ni = 0; ni < 4; ++ni)
        acc[mi][ni] = __builtin_amdgcn_mfma_f32_16x16x32_fp8_fp8((long)a3[mi], (long)b3[ni], acc[mi][ni], 0, 0, 0);
    __builtin_amdgcn_s_setprio(0);
    if (pf) {
      asm volatile("s_waitcnt vmcnt(0)" ::: "memory");   // c1 + B(T+1) landed
      WRITEA(1, nxtA);
      asm volatile("s_waitcnt lgkmcnt(0)" ::: "memory");
      PHASE_BAR();
    }
    curA = nxtA;
  }

  // epilogue: (acc/64) + bias, phi, fp8 out
#pragma unroll
  for (int mi = 0; mi < 4; ++mi) {
#pragma unroll
    for (int ni = 0; ni < 4; ++ni) {
      int col = bcol0 + wc * 64 + ni * 16 + lr;
      float bb = bias[col];
      float v[4];
#pragma unroll
      for (int i = 0; i < 4; ++i) {
        float x = acc[mi][ni][i] * 0.015625f + bb;
        v[i] = (x > 0.0f) ? (x + 1.0f) : __expf(x);
      }
      u32 w = enc4fp8(v[0], v[1], v[2], v[3]);
      size_t r0 = arow0 + wr * 64 + mi * 16 + g4 * 4;
      C[(r0 + 0) * TD2 + col] = (u8)w;
      C[(r0 + 1) * TD2 + col] = (u8)(w >> 8);
      C[(r0 + 2) * TD2 + col] = (u8)(w >> 16);
      C[(r0 + 3) * TD2 + col] = (u8)(w >> 24);
    }
  }
#undef STAGE_B
#undef LOADA
#undef WRITEA
}

// ---------------------------------------------------------------------------
// Attention qk-phases (r21, unchanged): raw fp8 LDS, HW decode at use.
__global__ __launch_bounds__(256) void k_attn_qk(
    const u8* __restrict__ qk,    // [M_,1536] fp8 (phi applied)
    float* __restrict__ AT,       // [B_,4,SP]
    float* __restrict__ AI,       // [B_,4,SP]
    float* __restrict__ sat)      // [4096,4]
{
  __shared__ u32 q8[S_ * 48];
  __shared__ u32 k8[S_ * 48];
  __shared__ float z[DH_], qt[DH_], qi[DH_];
  __shared__ float zqp[4][DH_];
  __shared__ float qip[4][DH_];
  __shared__ float wt[S_], wi[S_];
  __shared__ float at_l[S_ + 1], ai_l[S_ + 1];
  int t = threadIdx.x;
  int b = blockIdx.x >> 2, h = blockIdx.x & 3;
  size_t base = (size_t)b * S_ * TD2;
  int qoff = h * DH_, koff = 768 + h * DH_;
  int grp = t >> 4, gl = t & 15;
  int w = t >> 6, ln = t & 63;

#pragma unroll
  for (int j = 0; j < 4; ++j) {
    int c = j * 256 + t;
    int s = c / 12, cc = (c % 12) * 16;
    const u8* gq = qk + base + (size_t)s * TD2 + qoff + cc;
    const u8* gk = qk + base + (size_t)s * TD2 + koff + cc;
    char* dq = (char*)q8 + (size_t)(j * 256 + w * 64) * 16;
    char* dk = (char*)k8 + (size_t)(j * 256 + w * 64) * 16;
    if (c < NCH) {
      gload16(gq, dq);
      gload16(gk, dk);
    }
  }
  asm volatile("s_waitcnt vmcnt(0)" ::: "memory");
  __syncthreads();
  if (ln < 48) {
    int s0 = w * 18, s1 = (w == 3) ? S_ : (s0 + 18);
    float p[4] = {};
    for (int s = s0; s < s1; ++s) {
      float f[4];
      dec4f(k8[s * 48 + ln], f);
      p[0] += f[0]; p[1] += f[1]; p[2] += f[2]; p[3] += f[3];
    }
#pragma unroll
    for (int j = 0; j < 4; ++j) zqp[w][ln * 4 + j] = p[j];
  }
  __syncthreads();
  if (t < DH_) z[t] = (zqp[0][t] + zqp[1][t]) + (zqp[2][t] + zqp[3][t]);
  __syncthreads();
  for (int s = grp; s < S_; s += 16) {
    float f[12];
    int g0 = s * 48 + gl * 3;
    dec4f(q8[g0], f); dec4f(q8[g0 + 1], f + 4); dec4f(q8[g0 + 2], f + 8);
    float a = 0;
    int d0 = gl * 12;
#pragma unroll
    for (int i = 0; i < 12; ++i) a += f[i] * z[d0 + i];
#pragma unroll
    for (int o = 8; o >= 1; o >>= 1) a += __shfl_xor(a, o);
    if (gl == 0) {
      float den = a + 1e-6f;
      wt[s] = (s < TEXT_) ? 1.0f / (35.0f * den) : 0.0f;
      wi[s] = (s >= TEXT_) ? 1.0f / (36.0f * den) : 0.0f;
    }
  }
  __syncthreads();
  if (ln < 48) {
    int s0 = w * 18, s1 = (w == 3) ? S_ : (s0 + 18);
    float pt[4] = {}, pi[4] = {};
    for (int s = s0; s < s1; ++s) {
      float wts = wt[s], wis = wi[s];
      float f[4];
      dec4f(q8[s * 48 + ln], f);
#pragma unroll
      for (int j = 0; j < 4; ++j) { pt[j] += f[j] * wts; pi[j] += f[j] * wis; }
    }
#pragma unroll
    for (int j = 0; j < 4; ++j) { zqp[w][ln * 4 + j] = pt[j]; qip[w][ln * 4 + j] = pi[j]; }
  }
  __syncthreads();
  if (t < DH_) {
    qt[t] = (zqp[0][t] + zqp[1][t]) + (zqp[2][t] + zqp[3][t]);
    qi[t] = (qip[0][t] + qip[1][t]) + (qip[2][t] + qip[3][t]);
  }
  __syncthreads();
  size_t arow = ((size_t)b * 4 + h) * SP;
  for (int s = grp; s < S_; s += 16) {
    float f[12];
    int g0 = s * 48 + gl * 3;
    dec4f(k8[g0], f); dec4f(k8[g0 + 1], f + 4); dec4f(k8[g0 + 2], f + 8);
    float aT = 0, aI = 0;
    int d0 = gl * 12;
#pragma unroll
    for (int i = 0; i < 12; ++i) { aT += f[i] * qt[d0 + i]; aI += f[i] * qi[d0 + i]; }
#pragma unroll
    for (int o = 8; o >= 1; o >>= 1) { aT += __shfl_xor(aT, o); aI += __shfl_xor(aI, o); }
    if (gl == 0) {
      at_l[s] = aT; ai_l[s] = aI;
      AT[arow + s] = aT; AI[arow + s] = aI;
    }
  }
  __syncthreads();
  if (t < 64) {
    float vT = at_l[t] + ((t < 7) ? at_l[t + 64] : 0.0f);
    float vI = ai_l[t] + ((t < 7) ? ai_l[t + 64] : 0.0f);
#pragma unroll
    for (int o = 32; o >= 1; o >>= 1) { vT += __shfl_xor(vT, o); vI += __shfl_xor(vI, o); }
    if (t == 0) {
      sat[(size_t)b * 4 + h] = vT;
      sat[(size_t)(2048 + b) * 4 + h] = vI;
    }
  }
}

// ---------------------------------------------------------------------------
// Y accumulation (unchanged)
__global__ __launch_bounds__(192) void k_accy(
    const float* __restrict__ x,
    const float* __restrict__ AT,
    const float* __restrict__ AI,
    u16* __restrict__ Y)
{
  __shared__ float at_s[4][S_], ai_s[4][S_];
  int t = threadIdx.x, b = blockIdx.x;
  for (int i = t; i < 4 * S_; i += 192) {
    int h = i / S_, s = i % S_;
    at_s[h][s] = AT[((size_t)b * 4 + h) * SP + s];
    ai_s[h][s] = AI[((size_t)b * 4 + h) * SP + s];
  }
  __syncthreads();
  float4 yt[4] = {}, yi[4] = {};
  const float4* xb = (const float4*)(x + (size_t)b * S_ * 768);
  for (int s = 0; s < S_; ++s) {
    float4 xv = xb[s * 192 + t];
#pragma unroll
    for (int h = 0; h < 4; ++h) {
      float a = at_s[h][s], ai_ = ai_s[h][s];
      yt[h].x += a * xv.x; yt[h].y += a * xv.y; yt[h].z += a * xv.z; yt[h].w += a * xv.w;
      yi[h].x += ai_ * xv.x; yi[h].y += ai_ * xv.y; yi[h].z += ai_ * xv.z; yi[h].w += ai_ * xv.w;
    }
  }
  size_t rt = (size_t)b * 3072, ri = (size_t)(2048 + b) * 3072;
#pragma unroll
  for (int h = 0; h < 4; ++h) {
    uint2 ot, oi;
    ot.x = pk2bf(yt[h].x, yt[h].y); ot.y = pk2bf(yt[h].z, yt[h].w);
    oi.x = pk2bf(yi[h].x, yi[h].y); oi.y = pk2bf(yi[h].z, yi[h].w);
    *(uint2*)(&Y[rt + h * 768 + t * 4]) = ot;
    *(uint2*)(&Y[ri + h * 768 + t * 4]) = oi;
  }
}

// ---------------------------------------------------------------------------
// Grouped v-GEMM (B source now Wvbf [768][768] bf16 = v rows of w_qkv)
__global__ __launch_bounds__(256, 4) void k_gemm_v(
    const u16* __restrict__ Yb,    // [4096,3072] bf16
    const u16* __restrict__ Wvbf,  // [768,768] bf16 (Wv)
    const float* __restrict__ bqkv,
    const float* __restrict__ sat, // [4096,4]
    u16* __restrict__ G)           // [4096,768] bf16
{
  __shared__ u16 sm[24576];
  int t = threadIdx.x;
  int lane = t & 63, wid = t >> 6;
  int wr = wid >> 1, wc = wid & 1;
  int lr = lane & 15, g4 = lane >> 4;
  int bm = blockIdx.x / 12, nt = blockIdx.x % 12;
  int h = nt / 3, e0 = (nt % 3) * 64;
  const size_t arow0 = (size_t)bm * 128;

  const u16* srcA[4];
  int dA[4];
#pragma unroll
  for (int j = 0; j < 4; ++j) {
    int c = j * 256 + t;
    int row = c >> 3, kg = (c & 7) ^ (row & 7);
    srcA[j] = Yb + (arow0 + row) * 3072 + h * 768 + kg * 8;
    dA[j] = c * 8;
  }
  const u16* srcB[2];
  int dB[2];
#pragma unroll
  for (int j = 0; j < 2; ++j) {
    int c = j * 256 + t;
    int row = c >> 3, kg = (c & 7) ^ (row & 7);
    srcB[j] = Wvbf + (size_t)(h * DH_ + e0 + row) * 768 + kg * 8;
    dB[j] = c * 8;
  }

#define VSTAGE(abuf, bbuf, ktu) do { \
  gload16(srcA[0] + (ktu), &sm[(abuf) + dA[0]]); \
  gload16(srcA[1] + (ktu), &sm[(abuf) + dA[1]]); \
  gload16(srcA[2] + (ktu), &sm[(abuf) + dA[2]]); \
  gload16(srcA[3] + (ktu), &sm[(abuf) + dA[3]]); \
  gload16(srcB[0] + (ktu), &sm[(bbuf) + dB[0]]); \
  gload16(srcB[1] + (ktu), &sm[(bbuf) + dB[1]]); \
} while (0)

  int gx0 = g4 ^ (lr & 7);
  int aro = (wr * 64 + lr) * 64;
  int bro = (wc * 32 + lr) * 64;

  f32x4 acc[4][2] = {};

  VSTAGE(0, 16384, 0);
  asm volatile("s_waitcnt vmcnt(0)" ::: "memory");
  PHASE_BAR();

  for (int T = 0; T < NKT; ++T) {
    int abuf = (T & 1) * 8192, bbuf = 16384 + (T & 1) * 4096;
    bool pf = (T < NKT - 1);
    if (pf) VSTAGE(8192 - abuf, 20480 - (T & 1) * 4096, (T + 1) * 64);
#pragma unroll
    for (int kk = 0; kk < 2; ++kk) {
      int gx = gx0 ^ (kk * 4);
      bf16x8 a[4], bfr[2];
#pragma unroll
      for (int mi = 0; mi < 4; ++mi) a[mi] = *(const bf16x8*)(&sm[abuf + aro + mi * 1024 + gx * 8]);
#pragma unroll
      for (int ni = 0; ni < 2; ++ni) bfr[ni] = *(const bf16x8*)(&sm[bbuf + bro + ni * 1024 + gx * 8]);
#pragma unroll
      for (int mi = 0; mi < 4; ++mi)
#pragma unroll
        for (int ni = 0; ni < 2; ++ni)
          acc[mi][ni] = __builtin_amdgcn_mfma_f32_16x16x32_bf16(a[mi], bfr[ni], acc[mi][ni], 0, 0, 0);
    }
    if (pf) {
      asm volatile("s_waitcnt vmcnt(0)" ::: "memory");
      PHASE_BAR();
    }
  }

#pragma unroll
  for (int mi = 0; mi < 4; ++mi) {
#pragma unroll
    for (int ni = 0; ni < 2; ++ni) {
      int e = e0 + wc * 32 + ni * 16 + lr;
      int gcol = h * DH_ + e;
      float bv = bqkv[1536 + gcol];
#pragma unroll
      for (int i = 0; i < 4; ++i) {
        size_t row = arow0 + wr * 64 + mi * 16 + g4 * 4 + i;
        G[row * 768 + gcol] = f2bf(acc[mi][ni][i] + sat[row * 4 + h] * bv);
      }
    }
  }
#undef VSTAGE
}

// ---------------------------------------------------------------------------
// Head GEMM: F = tanh(G * w_out^T + b_out) (unchanged)
__global__ __launch_bounds__(512, 4) void k_gemm_head(
    const u16* __restrict__ Gb,
    const u16* __restrict__ Wo,
    const float* __restrict__ bout,
    u16* __restrict__ F)
{
  __shared__ u16 sm[32768];
  int t = threadIdx.x;
  int lane = t & 63, wid = t >> 6;
  int wr = wid >> 2, wc = wid & 3;
  int lr = lane & 15;
  int g4 = lane >> 4;

  int bm = blockIdx.x / 3, bn = blockIdx.x % 3;
  const size_t arow0 = (size_t)bm * 128;
  const int bcol0 = bn * 256;

  const u16* srcA[2];
  int dA[2];
#pragma unroll
  for (int j = 0; j < 2; ++j) {
    int c = j * 512 + t;
    srcA[j] = Gb + (arow0 + (c >> 3)) * 768 + ((c & 7) ^ ((c >> 3) & 7)) * 8;
    dA[j] = c * 8;
  }
  const u16* srcB[4];
  int dB[4];
#pragma unroll
  for (int j = 0; j < 4; ++j) {
    int c = j * 512 + t;
    srcB[j] = Wo + (size_t)(bcol0 + (c >> 3)) * 768 + ((c & 7) ^ ((c >> 3) & 7)) * 8;
    dB[j] = 16384 + c * 8;
  }

#define STAGE_A2(abuf, ktu) do { \
  gload16(srcA[0] + (ktu), &sm[(abuf) + dA[0]]); \
  gload16(srcA[1] + (ktu), &sm[(abuf) + dA[1]]); \
} while (0)
#define STAGE_B2(ktu) do { \
  gload16(srcB[0] + (ktu), &sm[dB[0]]); \
  gload16(srcB[1] + (ktu), &sm[dB[1]]); \
  gload16(srcB[2] + (ktu), &sm[dB[2]]); \
  gload16(srcB[3] + (ktu), &sm[dB[3]]); \
} while (0)

  int gx0 = g4 ^ (lr & 7);
  int aro = (wr * 64 + lr) * 64;
  int bro = 16384 + (wc * 64 + lr) * 64;

  f32x4 acc[4][4] = {};

  STAGE_A2(0, 0); STAGE_B2(0);
  asm volatile("s_waitcnt vmcnt(0)" ::: "memory");
  PHASE_BAR();

  int curA = 0;
  for (int T = 0; T < NKT; ++T) {
    int nxtA = 8192 - curA;
    bool pf = (T < NKT - 1);
    int ktu = (T + 1) * 64;
    bf16x8 bfr[4][2];
#pragma unroll
    for (int ni = 0; ni < 4; ++ni) {
      bfr[ni][0] = *(const bf16x8*)(&sm[bro + ni * 1024 + gx0 * 8]);
      bfr[ni][1] = *(const bf16x8*)(&sm[bro + ni * 1024 + (gx0 ^ 4) * 8]);
    }
    LGKM0();
    PHASE_BAR();
    if (pf) { STAGE_B2(ktu); STAGE_A2(nxtA, ktu); }
    __builtin_amdgcn_s_setprio(1);
#pragma unroll
    for (int kk = 0; kk < 2; ++kk) {
      int gx = gx0 ^ (kk * 4);
      bf16x8 afr[4];
#pragma unroll
      for (int mi = 0; mi < 4; ++mi)
        afr[mi] = *(const bf16x8*)(&sm[curA + aro + mi * 1024 + gx * 8]);
#pragma unroll
      for (int mi = 0; mi < 4; ++mi)
#pragma unroll
        for (int ni = 0; ni < 4; ++ni)
          acc[mi][ni] = __builtin_amdgcn_mfma_f32_16x16x32_bf16(afr[mi], bfr[ni][kk], acc[mi][ni], 0, 0, 0);
    }
    __builtin_amdgcn_s_setprio(0);
    if (pf) {
      asm volatile("s_waitcnt vmcnt(0)" ::: "memory");
      PHASE_BAR();
    }
    curA = nxtA;
  }

#pragma unroll
  for (int mi = 0; mi < 4; ++mi) {
#pragma unroll
    for (int ni = 0; ni < 4; ++ni) {
      int col = bcol0 + wc * 64 + ni * 16 + lr;
      float bb = bout[col];
#pragma unroll
      for (int i = 0; i < 4; ++i) {
        size_t row = arow0 + wr * 64 + mi * 16 + g4 * 4 + i;
        F[row * 768 + col] = f2bf(tanhf(acc[mi][ni][i] + bb));
      }
    }
  }
#undef STAGE_A2
#undef STAGE_B2
}

// ---------------------------------------------------------------------------
#define GC 4
__global__ __launch_bounds__(256) void k_cos(
    const u16* __restrict__ F,
    float* __restrict__ out)
{
  __shared__ float red[3][4];
  int t = threadIdx.x, b0 = blockIdx.x * GC;
  int lane = t & 63, wid = t >> 6;
  for (int g = 0; g < GC; ++g) {
    int b = b0 + g;
    float st = 0, si = 0, sd = 0;
#pragma unroll
    for (int j = 0; j < 3; ++j) {
      int c = t + j * 256;
      float rt = bf2f(F[(size_t)b * 768 + c]);
      float ri = bf2f(F[(size_t)(2048 + b) * 768 + c]);
      st += rt * rt; si += ri * ri; sd += rt * ri;
    }
#pragma unroll
    for (int off = 32; off >= 1; off >>= 1) {
      st += __shfl_down(st, off);
      si += __shfl_down(si, off);
      sd += __shfl_down(sd, off);
    }
    __syncthreads();
    if (lane == 0) { red[0][wid] = st; red[1][wid] = si; red[2][wid] = sd; }
    __syncthreads();
    if (t == 0) {
      float S1 = red[0][0] + red[0][1] + red[0][2] + red[0][3];
      float S2 = red[1][0] + red[1][1] + red[1][2] + red[1][3];
      float S3 = red[2][0] + red[2][1] + red[2][2] + red[2][3];
      out[b] = S3 / (fmaxf(sqrtf(S1), 1e-8f) * fmaxf(sqrtf(S2), 1e-8f));
    }
  }
}

// ---------------------------------------------------------------------------
extern "C" void kernel_launch(void* const* d_in, const int* in_sizes, int n_in,
                              void* d_out, int out_size, void* d_ws, size_t ws_size,
                              hipStream_t stream) {
  const float* features = (const float*)d_in[0];
  // d_in[1] = attention_mask (unused by forward)
  const float* w_qkv = (const float*)d_in[2];
  const float* b_qkv = (const float*)d_in[3];
  const float* w_out = (const float*)d_in[4];
  const float* b_out = (const float*)d_in[5];
  float* out = (float*)d_out;

  char* ws = (char*)d_ws;
  size_t off = 0;
  auto alloc = [&](size_t bytes) {
    void* p = ws + off;
    off += (bytes + 255) & ~(size_t)255;
    return p;
  };
  u8*  QK   = (u8*)alloc((size_t)M_ * TD2);          // 218 MB (fp8)
  u8*  Wf8  = (u8*)alloc((size_t)TD2 * D_);          // 1.2 MB (w*64 fp8)
  u16* Wvbf = (u16*)alloc((size_t)D_ * D_ * 2);      // 1.2 MB (Wv bf16)
  u16* Wobf = (u16*)alloc((size_t)D_ * D_ * 2);      // 1.2 MB
  u16* Yv   = (u16*)alloc((size_t)4096 * 3072 * 2);  // 25 MB
  float* AT = (float*)alloc((size_t)B_ * 4 * SP * 4); // 2.4 MB
  float* AI = (float*)alloc((size_t)B_ * 4 * SP * 4); // 2.4 MB
  float* sat = (float*)alloc((size_t)4096 * 4 * 4);  // 64 KB
  u16* G    = (u16*)alloc((size_t)4096 * D_ * 2);    // 6.3 MB
  u16* F    = (u16*)alloc((size_t)4096 * D_ * 2);    // 6.3 MB
  (void)ws_size;

  hipLaunchKernelGGL(k_cvt_w8, dim3((TD2 * D_ / 16 + 255) / 256), dim3(256), 0, stream,
                     w_qkv, Wf8, TD2 * D_ / 16);
  hipLaunchKernelGGL(k_cvt_bf16, dim3((D_ * D_ / 8 + 255) / 256), dim3(256), 0, stream,
                     w_qkv + (size_t)TD2 * D_, Wvbf, D_ * D_ / 8);
  hipLaunchKernelGGL(k_cvt_bf16, dim3((D_ * D_ / 8 + 255) / 256), dim3(256), 0, stream,
                     w_out, Wobf, D_ * D_ / 8);

  hipLaunchKernelGGL(k_gemm_qkv, dim3(6 * 1136), dim3(512), 0, stream,
                     features, Wf8, b_qkv, QK);
  hipLaunchKernelGGL(k_attn_qk, dim3(B_ * H_), dim3(256), 0, stream, QK, AT, AI, sat);
  hipLaunchKernelGGL(k_accy, dim3(B_), dim3(192), 0, stream, features, AT, AI, Yv);
  hipLaunchKernelGGL(k_gemm_v, dim3(32 * 12), dim3(256), 0, stream,
                     Yv, Wvbf, b_qkv, sat, G);
  hipLaunchKernelGGL(k_gemm_head, dim3(32 * 3), dim3(512), 0, stream,
                     G, Wobf, b_out, F);
  hipLaunchKernelGGL(k_cos, dim3(B_ / GC), dim3(256), 0, stream, F, out);
}